// Round 6
// baseline (706.869 us; speedup 1.0000x reference)
//
#include <hip/hip_runtime.h>

#define NN    50000
#define EE    800000
#define EPE   850000     // EE + NN self loops
#define NPAD  50048      // multiple of 64
#define BGR   64

typedef __attribute__((ext_vector_type(8))) short bf16x8;
typedef __attribute__((ext_vector_type(4))) float f32x4;

__device__ __forceinline__ float bf2f(unsigned short u) {
    return __uint_as_float(((unsigned)u) << 16);
}
__device__ __forceinline__ unsigned short f2bf(float f) {
    unsigned u = __float_as_uint(f);
    unsigned r = (u + 0x7FFFu + ((u >> 16) & 1u)) >> 16;
    return (unsigned short)r;
}
__device__ __forceinline__ float silu(float y) { return y / (1.f + __expf(-y)); }

// ---------------- weight transpose: WT[m][col][k] = f2bf(W[m][k][col]) ----------------
__global__ void transpose_w(const float* __restrict__ W0, const float* __restrict__ Wg,
                            unsigned short* __restrict__ WT) {
    __shared__ unsigned short tile[128][129];
    int m = blockIdx.x;
    const float* src = (m == 0) ? W0 : (Wg + (m - 1) * 16384);
    unsigned short* dst = WT + m * 16384;
    for (int i = threadIdx.x; i < 16384; i += 256) tile[i >> 7][i & 127] = f2bf(src[i]);
    __syncthreads();
    for (int i = threadIdx.x; i < 16384; i += 256) {
        int c = i >> 7, k = i & 127;
        dst[i] = tile[k][c];
    }
}

// ---------------- count in-degree + per-graph node histogram ----------------
__global__ void count_edges(const int* __restrict__ eidx, int* __restrict__ counts,
                            const int* __restrict__ batch, float* __restrict__ cntArr) {
    __shared__ float lh[BGR];
    bool doHist = (blockIdx.x < 196);
    int i = blockIdx.x * 256 + threadIdx.x;
    if (doHist) {
        if (threadIdx.x < BGR) lh[threadIdx.x] = 0.f;
        __syncthreads();
    }
    if (i < EPE) {
        int d = (i < EE) ? eidx[EE + i] : (i - EE);
        atomicAdd(&counts[d], 1);
    }
    if (doHist) {
        if (i < NN) atomicAdd(&lh[batch[i]], 1.f);
        __syncthreads();
        if (threadIdx.x < BGR) {
            float v = lh[threadIdx.x];
            if (v != 0.f) atomicAdd(&cntArr[threadIdx.x], v);
        }
    }
}

// ---------------- 3-kernel exclusive scan ----------------
__global__ void scan1(const int* __restrict__ counts, int* __restrict__ offs,
                      int* __restrict__ partials) {
    __shared__ int sm[256];
    int t = threadIdx.x, i = blockIdx.x * 256 + t;
    int x = (i < NN) ? counts[i] : 0;
    sm[t] = x; __syncthreads();
    for (int d = 1; d < 256; d <<= 1) {
        int v = (t >= d) ? sm[t - d] : 0;
        __syncthreads(); sm[t] += v; __syncthreads();
    }
    if (i < NN) offs[i] = sm[t] - x;
    if (t == 255) partials[blockIdx.x] = sm[255];
}

__global__ void scan2(int* __restrict__ partials, int nb) {
    __shared__ int sm[256];
    int t = threadIdx.x;
    int x = (t < nb) ? partials[t] : 0;
    sm[t] = x; __syncthreads();
    for (int d = 1; d < 256; d <<= 1) {
        int v = (t >= d) ? sm[t - d] : 0;
        __syncthreads(); sm[t] += v; __syncthreads();
    }
    if (t < nb) partials[t] = sm[t] - x;
}

__global__ void scan3(int* __restrict__ offs, const int* __restrict__ partials,
                      int* __restrict__ cursor) {
    int i = blockIdx.x * 256 + threadIdx.x;
    if (i < NN) {
        int v = offs[i] + partials[blockIdx.x];
        offs[i] = v; cursor[i] = v;
    }
    if (i == 0) offs[NN] = EPE;
}

__global__ void scatter_edges(const int* __restrict__ eidx, int* __restrict__ cursor,
                              int* __restrict__ csr) {
    int i = blockIdx.x * 256 + threadIdx.x;
    if (i >= EPE) return;
    int s, d;
    if (i < EE) { s = eidx[i]; d = eidx[EE + i]; } else { s = i - EE; d = i - EE; }
    int pos = atomicAdd(&cursor[d], 1);
    csr[pos] = s;
}

// ---------------- encoder GEMM: h(bf16) = silu(LN(x@W0 + b0)) ----------------
__global__ __launch_bounds__(256) void gemm_encoder(
    const float* __restrict__ x, const unsigned short* __restrict__ WT,
    const float* __restrict__ b0, const float* __restrict__ g0,
    const float* __restrict__ be0, unsigned short* __restrict__ h) {
    int wave = threadIdx.x >> 6, lane = threadIdx.x & 63;
    int cl = lane & 15, q = lane >> 4;
    int row0 = blockIdx.x * 64 + wave * 16;
    int rA = row0 + cl; if (rA >= NN) rA = NN - 1;
    int kq = q * 8;
    f32x4 acc[8];
#pragma unroll
    for (int t = 0; t < 8; ++t) acc[t] = (f32x4){0.f, 0.f, 0.f, 0.f};
#pragma unroll
    for (int k0 = 0; k0 < 128; k0 += 32) {
        const float* xr = x + rA * 128 + k0 + kq;
        f32x4 f0 = *(const f32x4*)(xr);
        f32x4 f1 = *(const f32x4*)(xr + 4);
        bf16x8 a;
#pragma unroll
        for (int j = 0; j < 4; ++j) {
            a[j] = (short)f2bf(f0[j]);
            a[4 + j] = (short)f2bf(f1[j]);
        }
#pragma unroll
        for (int t = 0; t < 8; ++t) {
            bf16x8 b = *(const bf16x8*)(WT + (t * 16 + cl) * 128 + k0 + kq);
            acc[t] = __builtin_amdgcn_mfma_f32_16x16x32_bf16(a, b, acc[t], 0, 0, 0);
        }
    }
    float bcol[8], gcol[8], becol[8];
#pragma unroll
    for (int t = 0; t < 8; ++t) {
        int c = t * 16 + cl;
        bcol[t] = b0[c]; gcol[t] = g0[c]; becol[t] = be0[c];
    }
#pragma unroll
    for (int r = 0; r < 4; ++r) {
        int row = row0 + q * 4 + r;
        float v[8], s = 0.f, ss = 0.f;
#pragma unroll
        for (int t = 0; t < 8; ++t) {
            v[t] = acc[t][r] + bcol[t];
            s += v[t]; ss += v[t] * v[t];
        }
#pragma unroll
        for (int m = 1; m <= 8; m <<= 1) {
            s += __shfl_xor(s, m, 64); ss += __shfl_xor(ss, m, 64);
        }
        float mu = s * (1.f / 128.f);
        float var = ss * (1.f / 128.f) - mu * mu;
        float rstd = rsqrtf(var + 1e-5f);
        if (row < NN) {
#pragma unroll
            for (int t = 0; t < 8; ++t) {
                float y = (v[t] - mu) * rstd * gcol[t] + becol[t];
                h[row * 128 + t * 16 + cl] = f2bf(silu(y));
            }
        }
    }
}

// ---------------- GAT GEMM: hh = h@Wg[l] (bf16), a_s/a_d/es per node ----------------
__global__ __launch_bounds__(256) void gemm_gat(
    const unsigned short* __restrict__ h, const unsigned short* __restrict__ WT,
    const float* __restrict__ atts, const float* __restrict__ attd,
    unsigned short* __restrict__ hh, float* __restrict__ a_s, float* __restrict__ a_d,
    float* __restrict__ es) {
    int wave = threadIdx.x >> 6, lane = threadIdx.x & 63;
    int cl = lane & 15, q = lane >> 4;
    int row0 = blockIdx.x * 64 + wave * 16;
    int rA = row0 + cl; if (rA >= NN) rA = NN - 1;
    int kq = q * 8;
    f32x4 acc[8];
#pragma unroll
    for (int t = 0; t < 8; ++t) acc[t] = (f32x4){0.f, 0.f, 0.f, 0.f};
#pragma unroll
    for (int k0 = 0; k0 < 128; k0 += 32) {
        bf16x8 a = *(const bf16x8*)(h + rA * 128 + k0 + kq);
#pragma unroll
        for (int t = 0; t < 8; ++t) {
            bf16x8 b = *(const bf16x8*)(WT + (t * 16 + cl) * 128 + k0 + kq);
            acc[t] = __builtin_amdgcn_mfma_f32_16x16x32_bf16(a, b, acc[t], 0, 0, 0);
        }
    }
#pragma unroll
    for (int r = 0; r < 4; ++r) {
        int row = row0 + q * 4 + r;
        if (row < NN) {
#pragma unroll
            for (int t = 0; t < 8; ++t)
                hh[row * 128 + t * 16 + cl] = f2bf(acc[t][r]);
        }
    }
    float as_lo[4], as_hi[4], ad_lo[4], ad_hi[4];
#pragma unroll
    for (int hd = 0; hd < 4; ++hd) {
        as_lo[hd] = atts[hd * 32 + cl];      as_hi[hd] = atts[hd * 32 + 16 + cl];
        ad_lo[hd] = attd[hd * 32 + cl];      ad_hi[hd] = attd[hd * 32 + 16 + cl];
    }
#pragma unroll
    for (int r = 0; r < 4; ++r) {
        int row = row0 + q * 4 + r;
        float ps[4], pd[4];
#pragma unroll
        for (int hd = 0; hd < 4; ++hd) {
            float v0 = acc[2 * hd][r], v1 = acc[2 * hd + 1][r];
            ps[hd] = v0 * as_lo[hd] + v1 * as_hi[hd];
            pd[hd] = v0 * ad_lo[hd] + v1 * ad_hi[hd];
        }
#pragma unroll
        for (int m = 1; m <= 8; m <<= 1) {
#pragma unroll
            for (int hd = 0; hd < 4; ++hd) {
                ps[hd] += __shfl_xor(ps[hd], m, 64);
                pd[hd] += __shfl_xor(pd[hd], m, 64);
            }
        }
        if (row < NN && cl < 4) {
            float vs = (cl == 0) ? ps[0] : (cl == 1) ? ps[1] : (cl == 2) ? ps[2] : ps[3];
            float vd = (cl == 0) ? pd[0] : (cl == 1) ? pd[1] : (cl == 2) ? pd[2] : pd[3];
            a_s[row * 4 + cl] = vs;
            a_d[row * 4 + cl] = vd;
            float e = vs + vd;                       // self-loop logit
            es[row * 4 + cl] = (e > 0.f) ? e : 0.2f * e;
        }
    }
}

// ---------------- aggregation: block=1 node, 4 waves split edges; LN; optional pool ----
__global__ __launch_bounds__(256) void gat_aggregate(
    const int* __restrict__ offs, const int* __restrict__ csr,
    const float* __restrict__ a_s, const float* __restrict__ a_d,
    const float* __restrict__ es, const unsigned short* __restrict__ hh,
    unsigned short* __restrict__ h,
    const float* __restrict__ bg, const float* __restrict__ gg,
    const float* __restrict__ bgg,
    const int* __restrict__ batch, float* __restrict__ pooled) {
    __shared__ f32x4 lw[4][64];
    __shared__ float2 cb[4][64];
    __shared__ float dns[4][4];
    int node = blockIdx.x;
    int wv = threadIdx.x >> 6, lane = threadIdx.x & 63;
    int e0 = offs[node], e1 = offs[node + 1];
    int cnt = e1 - e0;
    int qn = (cnt + 3) >> 2;
    int ws = e0 + wv * qn; if (ws > e1) ws = e1;
    int we = ws + qn; if (we > e1) we = e1;
    int c0 = lane * 2, hd = lane >> 4;
    f32x4 ad4 = *(const f32x4*)(a_d + node * 4);
    f32x4 e4  = *(const f32x4*)(es  + node * 4);
    float d0 = 0.f, d1 = 0.f, d2 = 0.f, d3 = 0.f;
    float x0 = 0.f, y0 = 0.f, x1 = 0.f, y1 = 0.f;
    float x2 = 0.f, y2 = 0.f, x3 = 0.f, y3 = 0.f;
    for (int base = ws; base < we; base += 64) {
        int cend = min(we, base + 64);
        // phase A: lanes compute softmax weights (all 4 heads) for this wave's chunk
        for (int e = base + lane; e < cend; e += 64) {
            int s = csr[e];
            f32x4 as = *(const f32x4*)(a_s + s * 4);
            f32x4 o;
#pragma unroll
            for (int k = 0; k < 4; ++k) {
                float qq = as[k] + ad4[k];
                qq = (qq > 0.f) ? qq : 0.2f * qq;
                o[k] = __expf(qq - e4[k]);
            }
            lw[wv][e - base] = o;
        }
        asm volatile("s_waitcnt lgkmcnt(0)" ::: "memory");
        // phase B: serial weighted accumulation over the chunk
        int e = base;
        for (; e + 4 <= cend; e += 4) {
            int s0 = csr[e], s1 = csr[e + 1], s2 = csr[e + 2], s3 = csr[e + 3];
            float w0 = lw[wv][e - base + 0][hd];
            float w1 = lw[wv][e - base + 1][hd];
            float w2 = lw[wv][e - base + 2][hd];
            float w3 = lw[wv][e - base + 3][hd];
            unsigned v0 = *(const unsigned*)(hh + s0 * 128 + c0);
            unsigned v1 = *(const unsigned*)(hh + s1 * 128 + c0);
            unsigned v2 = *(const unsigned*)(hh + s2 * 128 + c0);
            unsigned v3 = *(const unsigned*)(hh + s3 * 128 + c0);
            d0 += w0; x0 += w0 * bf2f((unsigned short)(v0 & 0xFFFFu)); y0 += w0 * bf2f((unsigned short)(v0 >> 16));
            d1 += w1; x1 += w1 * bf2f((unsigned short)(v1 & 0xFFFFu)); y1 += w1 * bf2f((unsigned short)(v1 >> 16));
            d2 += w2; x2 += w2 * bf2f((unsigned short)(v2 & 0xFFFFu)); y2 += w2 * bf2f((unsigned short)(v2 >> 16));
            d3 += w3; x3 += w3 * bf2f((unsigned short)(v3 & 0xFFFFu)); y3 += w3 * bf2f((unsigned short)(v3 >> 16));
        }
        for (; e < cend; ++e) {
            int s0 = csr[e];
            float w0 = lw[wv][e - base][hd];
            unsigned v0 = *(const unsigned*)(hh + s0 * 128 + c0);
            d0 += w0; x0 += w0 * bf2f((unsigned short)(v0 & 0xFFFFu)); y0 += w0 * bf2f((unsigned short)(v0 >> 16));
        }
        if (cend < we)
            asm volatile("s_waitcnt lgkmcnt(0)" ::: "memory");
    }
    cb[wv][lane] = make_float2((x0 + x1) + (x2 + x3), (y0 + y1) + (y2 + y3));
    if (lane == hd * 16) dns[wv][hd] = (d0 + d1) + (d2 + d3);
    __syncthreads();
    if (wv == 0) {
        float X = cb[0][lane].x + cb[1][lane].x + cb[2][lane].x + cb[3][lane].x;
        float Y = cb[0][lane].y + cb[1][lane].y + cb[2][lane].y + cb[3][lane].y;
        float D = (dns[0][hd] + dns[1][hd]) + (dns[2][hd] + dns[3][hd]);
        float inv = 1.f / D;
        float o0 = X * inv + bg[c0];
        float o1 = Y * inv + bg[c0 + 1];
        float s = o0 + o1, ss = o0 * o0 + o1 * o1;
#pragma unroll
        for (int m = 1; m <= 32; m <<= 1) {
            s += __shfl_xor(s, m, 64); ss += __shfl_xor(ss, m, 64);
        }
        float mu = s * (1.f / 128.f);
        float var = ss * (1.f / 128.f) - mu * mu;
        float rstd = rsqrtf(var + 1e-5f);
        float yy0 = (o0 - mu) * rstd * gg[c0] + bgg[c0];
        float yy1 = (o1 - mu) * rstd * gg[c0 + 1] + bgg[c0 + 1];
        unsigned idpk = *(const unsigned*)(h + node * 128 + c0);
        float r0 = silu(yy0) + bf2f((unsigned short)(idpk & 0xFFFFu));
        float r1 = silu(yy1) + bf2f((unsigned short)(idpk >> 16));
        unsigned pk = (unsigned)f2bf(r0) | ((unsigned)f2bf(r1) << 16);
        *(unsigned*)(h + node * 128 + c0) = pk;
        if (pooled) {
            int g = batch[node];
            atomicAdd(&pooled[g * 128 + c0], r0);
            atomicAdd(&pooled[g * 128 + c0 + 1], r1);
        }
    }
}

// ---------------- head: silu(LN(pooled/cnt @ Wp + bp)) -> f32 out ----------------
__global__ void final_kernel(const float* __restrict__ pooled, const float* __restrict__ cntArr,
                             const float* __restrict__ Wp, const float* __restrict__ bp,
                             const float* __restrict__ gp, const float* __restrict__ bep,
                             float* __restrict__ out) {
    __shared__ float p[128];
    __shared__ float red[128];
    int g = blockIdx.x, c = threadIdx.x;
    float cnt = cntArr[g]; if (cnt < 1.f) cnt = 1.f;
    p[c] = pooled[g * 128 + c] / cnt;
    __syncthreads();
    float acc = bp[c];
    for (int k = 0; k < 128; ++k) acc += p[k] * Wp[k * 128 + c];
    red[c] = acc;
    __syncthreads();
    if (c < 64) {
        float s = red[c] + red[c + 64];
#pragma unroll
        for (int m = 1; m <= 32; m <<= 1) s += __shfl_xor(s, m, 64);
        if (c == 0) red[0] = s;
    }
    __syncthreads();
    float mu = red[0] * (1.f / 128.f);
    __syncthreads();
    float dv = acc - mu;
    red[c] = dv * dv;
    __syncthreads();
    if (c < 64) {
        float s = red[c] + red[c + 64];
#pragma unroll
        for (int m = 1; m <= 32; m <<= 1) s += __shfl_xor(s, m, 64);
        if (c == 0) red[0] = s;
    }
    __syncthreads();
    float var = red[0] * (1.f / 128.f);
    float rstd = rsqrtf(var + 1e-5f);
    float y = dv * rstd * gp[c] + bep[c];
    out[g * 128 + c] = silu(y);
}

extern "C" void kernel_launch(void* const* d_in, const int* in_sizes, int n_in,
                              void* d_out, int out_size, void* d_ws, size_t ws_size,
                              hipStream_t stream) {
    const float* x    = (const float*)d_in[0];
    const int*   eidx = (const int*)d_in[1];
    const int*   batch= (const int*)d_in[2];
    const float* W0   = (const float*)d_in[3];
    const float* b0   = (const float*)d_in[4];
    const float* g0   = (const float*)d_in[5];
    const float* be0  = (const float*)d_in[6];
    const float* Wg   = (const float*)d_in[7];
    const float* atts = (const float*)d_in[8];
    const float* attd = (const float*)d_in[9];
    const float* bg   = (const float*)d_in[10];
    const float* gg   = (const float*)d_in[11];
    const float* bgg  = (const float*)d_in[12];
    const float* Wp   = (const float*)d_in[13];
    const float* bp   = (const float*)d_in[14];
    const float* gp   = (const float*)d_in[15];
    const float* bep  = (const float*)d_in[16];

    char* ws = (char*)d_ws;
    size_t off = 0;
    auto alloc = [&](size_t bytes) {
        void* p = ws + off;
        off = (off + bytes + 255) & ~(size_t)255;
        return p;
    };
    unsigned short* h       = (unsigned short*)alloc((size_t)NPAD * 128 * 2);
    unsigned short* hh      = (unsigned short*)alloc((size_t)NN * 128 * 2);
    float*          a_s     = (float*)alloc((size_t)NN * 4 * 4);
    float*          a_d     = (float*)alloc((size_t)NN * 4 * 4);
    float*          es      = (float*)alloc((size_t)NN * 4 * 4);
    int*            offs    = (int*)alloc((size_t)(NN + 1) * 4);
    int*            cursor  = (int*)alloc((size_t)NN * 4);
    int*            counts  = (int*)alloc((size_t)NN * 4);
    int*            csr     = (int*)alloc((size_t)EPE * 4);
    int*            parts   = (int*)alloc(256 * 4);
    unsigned short* WT      = (unsigned short*)alloc(4 * 16384 * 2);
    float*          pooled  = (float*)alloc((size_t)(BGR * 128 + BGR) * 4);
    float*          cntArr  = pooled + BGR * 128;

    hipMemsetAsync(counts, 0, (size_t)NN * 4, stream);
    hipMemsetAsync(pooled, 0, (size_t)(BGR * 128 + BGR) * 4, stream);

    transpose_w<<<4, 256, 0, stream>>>(W0, Wg, WT);
    count_edges<<<(EPE + 255) / 256, 256, 0, stream>>>(eidx, counts, batch, cntArr);
    int nb = (NN + 255) / 256;
    scan1<<<nb, 256, 0, stream>>>(counts, offs, parts);
    scan2<<<1, 256, 0, stream>>>(parts, nb);
    scan3<<<nb, 256, 0, stream>>>(offs, parts, cursor);
    scatter_edges<<<(EPE + 255) / 256, 256, 0, stream>>>(eidx, cursor, csr);

    gemm_encoder<<<NPAD / 64, 256, 0, stream>>>(x, WT, b0, g0, be0, h);
    for (int l = 0; l < 3; ++l) {
        gemm_gat<<<NPAD / 64, 256, 0, stream>>>(h, WT + (l + 1) * 16384,
                                                atts + l * 128, attd + l * 128,
                                                hh, a_s, a_d, es);
        gat_aggregate<<<NN, 256, 0, stream>>>(offs, csr, a_s, a_d, es, hh, h,
                                              bg + l * 128, gg + l * 128, bgg + l * 128,
                                              batch, (l == 2) ? pooled : nullptr);
    }
    final_kernel<<<BGR, 128, 0, stream>>>(pooled, cntArr, Wp, bp, gp, bep, (float*)d_out);
}

// Round 7
// 627.107 us; speedup vs baseline: 1.1272x; 1.1272x over previous
//
#include <hip/hip_runtime.h>

#define NN    50000
#define EE    800000
#define EPE   850000     // EE + NN self loops
#define NPAD  50048      // multiple of 64
#define BGR   64
#define MAXCH 128        // edge chunk per node held in LDS

typedef __attribute__((ext_vector_type(8))) short bf16x8;
typedef __attribute__((ext_vector_type(4))) float f32x4;

__device__ __forceinline__ float bf2f(unsigned short u) {
    return __uint_as_float(((unsigned)u) << 16);
}
__device__ __forceinline__ unsigned short f2bf(float f) {
    unsigned u = __float_as_uint(f);
    unsigned r = (u + 0x7FFFu + ((u >> 16) & 1u)) >> 16;
    return (unsigned short)r;
}
__device__ __forceinline__ float silu(float y) { return y / (1.f + __expf(-y)); }

// ---------------- weight transpose: WT[m][col][k] = f2bf(W[m][k][col]) ----------------
__global__ void transpose_w(const float* __restrict__ W0, const float* __restrict__ Wg,
                            unsigned short* __restrict__ WT) {
    __shared__ unsigned short tile[128][129];
    int m = blockIdx.x;
    const float* src = (m == 0) ? W0 : (Wg + (m - 1) * 16384);
    unsigned short* dst = WT + m * 16384;
    for (int i = threadIdx.x; i < 16384; i += 256) tile[i >> 7][i & 127] = f2bf(src[i]);
    __syncthreads();
    for (int i = threadIdx.x; i < 16384; i += 256) {
        int c = i >> 7, k = i & 127;
        dst[i] = tile[k][c];
    }
}

// ---------------- count in-degree + per-graph node histogram ----------------
__global__ void count_edges(const int* __restrict__ eidx, int* __restrict__ counts,
                            const int* __restrict__ batch, float* __restrict__ cntArr) {
    __shared__ float lh[BGR];
    bool doHist = (blockIdx.x < 196);
    int i = blockIdx.x * 256 + threadIdx.x;
    if (doHist) {
        if (threadIdx.x < BGR) lh[threadIdx.x] = 0.f;
        __syncthreads();
    }
    if (i < EPE) {
        int d = (i < EE) ? eidx[EE + i] : (i - EE);
        atomicAdd(&counts[d], 1);
    }
    if (doHist) {
        if (i < NN) atomicAdd(&lh[batch[i]], 1.f);
        __syncthreads();
        if (threadIdx.x < BGR) {
            float v = lh[threadIdx.x];
            if (v != 0.f) atomicAdd(&cntArr[threadIdx.x], v);
        }
    }
}

// ---------------- 3-kernel exclusive scan ----------------
__global__ void scan1(const int* __restrict__ counts, int* __restrict__ offs,
                      int* __restrict__ partials) {
    __shared__ int sm[256];
    int t = threadIdx.x, i = blockIdx.x * 256 + t;
    int x = (i < NN) ? counts[i] : 0;
    sm[t] = x; __syncthreads();
    for (int d = 1; d < 256; d <<= 1) {
        int v = (t >= d) ? sm[t - d] : 0;
        __syncthreads(); sm[t] += v; __syncthreads();
    }
    if (i < NN) offs[i] = sm[t] - x;
    if (t == 255) partials[blockIdx.x] = sm[255];
}

__global__ void scan2(int* __restrict__ partials, int nb) {
    __shared__ int sm[256];
    int t = threadIdx.x;
    int x = (t < nb) ? partials[t] : 0;
    sm[t] = x; __syncthreads();
    for (int d = 1; d < 256; d <<= 1) {
        int v = (t >= d) ? sm[t - d] : 0;
        __syncthreads(); sm[t] += v; __syncthreads();
    }
    if (t < nb) partials[t] = sm[t] - x;
}

__global__ void scan3(int* __restrict__ offs, const int* __restrict__ partials,
                      int* __restrict__ cursor) {
    int i = blockIdx.x * 256 + threadIdx.x;
    if (i < NN) {
        int v = offs[i] + partials[blockIdx.x];
        offs[i] = v; cursor[i] = v;
    }
    if (i == 0) offs[NN] = EPE;
}

__global__ void scatter_edges(const int* __restrict__ eidx, int* __restrict__ cursor,
                              int* __restrict__ csr) {
    int i = blockIdx.x * 256 + threadIdx.x;
    if (i >= EPE) return;
    int s, d;
    if (i < EE) { s = eidx[i]; d = eidx[EE + i]; } else { s = i - EE; d = i - EE; }
    int pos = atomicAdd(&cursor[d], 1);
    __builtin_nontemporal_store(s, csr + pos);   // no-allocate: cut write amplification
}

// ---------------- encoder GEMM: h(bf16) = silu(LN(x@W0 + b0)) ----------------
__global__ __launch_bounds__(256) void gemm_encoder(
    const float* __restrict__ x, const unsigned short* __restrict__ WT,
    const float* __restrict__ b0, const float* __restrict__ g0,
    const float* __restrict__ be0, unsigned short* __restrict__ h) {
    int wave = threadIdx.x >> 6, lane = threadIdx.x & 63;
    int cl = lane & 15, q = lane >> 4;
    int row0 = blockIdx.x * 64 + wave * 16;
    int rA = row0 + cl; if (rA >= NN) rA = NN - 1;
    int kq = q * 8;
    f32x4 acc[8];
#pragma unroll
    for (int t = 0; t < 8; ++t) acc[t] = (f32x4){0.f, 0.f, 0.f, 0.f};
#pragma unroll
    for (int k0 = 0; k0 < 128; k0 += 32) {
        const float* xr = x + rA * 128 + k0 + kq;
        f32x4 f0 = *(const f32x4*)(xr);
        f32x4 f1 = *(const f32x4*)(xr + 4);
        bf16x8 a;
#pragma unroll
        for (int j = 0; j < 4; ++j) {
            a[j] = (short)f2bf(f0[j]);
            a[4 + j] = (short)f2bf(f1[j]);
        }
#pragma unroll
        for (int t = 0; t < 8; ++t) {
            bf16x8 b = *(const bf16x8*)(WT + (t * 16 + cl) * 128 + k0 + kq);
            acc[t] = __builtin_amdgcn_mfma_f32_16x16x32_bf16(a, b, acc[t], 0, 0, 0);
        }
    }
    float bcol[8], gcol[8], becol[8];
#pragma unroll
    for (int t = 0; t < 8; ++t) {
        int c = t * 16 + cl;
        bcol[t] = b0[c]; gcol[t] = g0[c]; becol[t] = be0[c];
    }
#pragma unroll
    for (int r = 0; r < 4; ++r) {
        int row = row0 + q * 4 + r;
        float v[8], s = 0.f, ss = 0.f;
#pragma unroll
        for (int t = 0; t < 8; ++t) {
            v[t] = acc[t][r] + bcol[t];
            s += v[t]; ss += v[t] * v[t];
        }
#pragma unroll
        for (int m = 1; m <= 8; m <<= 1) {
            s += __shfl_xor(s, m, 64); ss += __shfl_xor(ss, m, 64);
        }
        float mu = s * (1.f / 128.f);
        float var = ss * (1.f / 128.f) - mu * mu;
        float rstd = rsqrtf(var + 1e-5f);
        if (row < NN) {
#pragma unroll
            for (int t = 0; t < 8; ++t) {
                float y = (v[t] - mu) * rstd * gcol[t] + becol[t];
                h[row * 128 + t * 16 + cl] = f2bf(silu(y));
            }
        }
    }
}

// ---------------- GAT GEMM: hh = h@Wg[l] (bf16), a_s/a_d/es per node ----------------
__global__ __launch_bounds__(256) void gemm_gat(
    const unsigned short* __restrict__ h, const unsigned short* __restrict__ WT,
    const float* __restrict__ atts, const float* __restrict__ attd,
    unsigned short* __restrict__ hh, float* __restrict__ a_s, float* __restrict__ a_d,
    float* __restrict__ es) {
    int wave = threadIdx.x >> 6, lane = threadIdx.x & 63;
    int cl = lane & 15, q = lane >> 4;
    int row0 = blockIdx.x * 64 + wave * 16;
    int rA = row0 + cl; if (rA >= NN) rA = NN - 1;
    int kq = q * 8;
    f32x4 acc[8];
#pragma unroll
    for (int t = 0; t < 8; ++t) acc[t] = (f32x4){0.f, 0.f, 0.f, 0.f};
#pragma unroll
    for (int k0 = 0; k0 < 128; k0 += 32) {
        bf16x8 a = *(const bf16x8*)(h + rA * 128 + k0 + kq);
#pragma unroll
        for (int t = 0; t < 8; ++t) {
            bf16x8 b = *(const bf16x8*)(WT + (t * 16 + cl) * 128 + k0 + kq);
            acc[t] = __builtin_amdgcn_mfma_f32_16x16x32_bf16(a, b, acc[t], 0, 0, 0);
        }
    }
#pragma unroll
    for (int r = 0; r < 4; ++r) {
        int row = row0 + q * 4 + r;
        if (row < NN) {
#pragma unroll
            for (int t = 0; t < 8; ++t)
                hh[row * 128 + t * 16 + cl] = f2bf(acc[t][r]);
        }
    }
    float as_lo[4], as_hi[4], ad_lo[4], ad_hi[4];
#pragma unroll
    for (int hd = 0; hd < 4; ++hd) {
        as_lo[hd] = atts[hd * 32 + cl];      as_hi[hd] = atts[hd * 32 + 16 + cl];
        ad_lo[hd] = attd[hd * 32 + cl];      ad_hi[hd] = attd[hd * 32 + 16 + cl];
    }
#pragma unroll
    for (int r = 0; r < 4; ++r) {
        int row = row0 + q * 4 + r;
        float ps[4], pd[4];
#pragma unroll
        for (int hd = 0; hd < 4; ++hd) {
            float v0 = acc[2 * hd][r], v1 = acc[2 * hd + 1][r];
            ps[hd] = v0 * as_lo[hd] + v1 * as_hi[hd];
            pd[hd] = v0 * ad_lo[hd] + v1 * ad_hi[hd];
        }
#pragma unroll
        for (int m = 1; m <= 8; m <<= 1) {
#pragma unroll
            for (int hd = 0; hd < 4; ++hd) {
                ps[hd] += __shfl_xor(ps[hd], m, 64);
                pd[hd] += __shfl_xor(pd[hd], m, 64);
            }
        }
        if (row < NN && cl < 4) {
            float vs = (cl == 0) ? ps[0] : (cl == 1) ? ps[1] : (cl == 2) ? ps[2] : ps[3];
            float vd = (cl == 0) ? pd[0] : (cl == 1) ? pd[1] : (cl == 2) ? pd[2] : pd[3];
            a_s[row * 4 + cl] = vs;
            a_d[row * 4 + cl] = vd;
            float e = vs + vd;                       // self-loop logit
            es[row * 4 + cl] = (e > 0.f) ? e : 0.2f * e;
        }
    }
}

// ---------------- aggregation: wave per node (4/block), LDS weights+idx, 8-deep ILP ---
__global__ __launch_bounds__(256) void gat_aggregate(
    const int* __restrict__ offs, const int* __restrict__ csr,
    const float* __restrict__ a_s, const float* __restrict__ a_d,
    const float* __restrict__ es, const unsigned short* __restrict__ hh,
    unsigned short* __restrict__ h,
    const float* __restrict__ bg, const float* __restrict__ gg,
    const float* __restrict__ bgg,
    const int* __restrict__ batch, float* __restrict__ pooled) {
    __shared__ f32x4 lw[4][MAXCH];
    __shared__ int   ls[4][MAXCH];
    int wv = threadIdx.x >> 6;
    int node = blockIdx.x * 4 + wv;
    int lane = threadIdx.x & 63;
    if (node >= NN) return;
    int e0 = offs[node], e1 = offs[node + 1];
    int c0 = lane * 2, hd = lane >> 4;
    f32x4 ad4 = *(const f32x4*)(a_d + node * 4);
    f32x4 e4  = *(const f32x4*)(es  + node * 4);
    float dd[8], xx[8], yy[8];
#pragma unroll
    for (int u = 0; u < 8; ++u) { dd[u] = 0.f; xx[u] = 0.f; yy[u] = 0.f; }
    for (int base = e0; base < e1; base += MAXCH) {
        int cend = min(e1, base + MAXCH);
        // phase A: lanes compute softmax weights (all 4 heads) + stash src idx
        for (int e = base + lane; e < cend; e += 64) {
            int s = csr[e];
            f32x4 as = *(const f32x4*)(a_s + s * 4);
            f32x4 o;
#pragma unroll
            for (int k = 0; k < 4; ++k) {
                float qq = as[k] + ad4[k];
                qq = (qq > 0.f) ? qq : 0.2f * qq;
                o[k] = __expf(qq - e4[k]);
            }
            lw[wv][e - base] = o;
            ls[wv][e - base] = s;
        }
        asm volatile("s_waitcnt lgkmcnt(0)" ::: "memory");
        // phase B: 8 independent accumulation chains (gather latency hiding)
        int n = cend - base;
        int j = 0;
        for (; j + 8 <= n; j += 8) {
#pragma unroll
            for (int u = 0; u < 8; ++u) {
                int s = ls[wv][j + u];
                float wg = lw[wv][j + u][hd];
                unsigned v = *(const unsigned*)(hh + s * 128 + c0);
                dd[u] += wg;
                xx[u] += wg * bf2f((unsigned short)(v & 0xFFFFu));
                yy[u] += wg * bf2f((unsigned short)(v >> 16));
            }
        }
        for (; j < n; ++j) {
            int s = ls[wv][j];
            float wg = lw[wv][j][hd];
            unsigned v = *(const unsigned*)(hh + s * 128 + c0);
            dd[0] += wg;
            xx[0] += wg * bf2f((unsigned short)(v & 0xFFFFu));
            yy[0] += wg * bf2f((unsigned short)(v >> 16));
        }
        if (cend < e1)
            asm volatile("s_waitcnt lgkmcnt(0)" ::: "memory");
    }
    float D = ((dd[0] + dd[1]) + (dd[2] + dd[3])) + ((dd[4] + dd[5]) + (dd[6] + dd[7]));
    float X = ((xx[0] + xx[1]) + (xx[2] + xx[3])) + ((xx[4] + xx[5]) + (xx[6] + xx[7]));
    float Y = ((yy[0] + yy[1]) + (yy[2] + yy[3])) + ((yy[4] + yy[5]) + (yy[6] + yy[7]));
    float inv = 1.f / D;
    float o0 = X * inv + bg[c0];
    float o1 = Y * inv + bg[c0 + 1];
    float s = o0 + o1, ss = o0 * o0 + o1 * o1;
#pragma unroll
    for (int m = 1; m <= 32; m <<= 1) {
        s += __shfl_xor(s, m, 64); ss += __shfl_xor(ss, m, 64);
    }
    float mu = s * (1.f / 128.f);
    float var = ss * (1.f / 128.f) - mu * mu;
    float rstd = rsqrtf(var + 1e-5f);
    float yy0 = (o0 - mu) * rstd * gg[c0] + bgg[c0];
    float yy1 = (o1 - mu) * rstd * gg[c0 + 1] + bgg[c0 + 1];
    unsigned idpk = *(const unsigned*)(h + node * 128 + c0);
    float r0 = silu(yy0) + bf2f((unsigned short)(idpk & 0xFFFFu));
    float r1 = silu(yy1) + bf2f((unsigned short)(idpk >> 16));
    unsigned pk = (unsigned)f2bf(r0) | ((unsigned)f2bf(r1) << 16);
    *(unsigned*)(h + node * 128 + c0) = pk;
    if (pooled) {
        int g = batch[node];
        atomicAdd(&pooled[g * 128 + c0], r0);
        atomicAdd(&pooled[g * 128 + c0 + 1], r1);
    }
}

// ---------------- head: silu(LN(pooled/cnt @ Wp + bp)) -> f32 out ----------------
__global__ void final_kernel(const float* __restrict__ pooled, const float* __restrict__ cntArr,
                             const float* __restrict__ Wp, const float* __restrict__ bp,
                             const float* __restrict__ gp, const float* __restrict__ bep,
                             float* __restrict__ out) {
    __shared__ float p[128];
    __shared__ float red[128];
    int g = blockIdx.x, c = threadIdx.x;
    float cnt = cntArr[g]; if (cnt < 1.f) cnt = 1.f;
    p[c] = pooled[g * 128 + c] / cnt;
    __syncthreads();
    float acc = bp[c];
    for (int k = 0; k < 128; ++k) acc += p[k] * Wp[k * 128 + c];
    red[c] = acc;
    __syncthreads();
    if (c < 64) {
        float s = red[c] + red[c + 64];
#pragma unroll
        for (int m = 1; m <= 32; m <<= 1) s += __shfl_xor(s, m, 64);
        if (c == 0) red[0] = s;
    }
    __syncthreads();
    float mu = red[0] * (1.f / 128.f);
    __syncthreads();
    float dv = acc - mu;
    red[c] = dv * dv;
    __syncthreads();
    if (c < 64) {
        float s = red[c] + red[c + 64];
#pragma unroll
        for (int m = 1; m <= 32; m <<= 1) s += __shfl_xor(s, m, 64);
        if (c == 0) red[0] = s;
    }
    __syncthreads();
    float var = red[0] * (1.f / 128.f);
    float rstd = rsqrtf(var + 1e-5f);
    float y = dv * rstd * gp[c] + bep[c];
    out[g * 128 + c] = silu(y);
}

extern "C" void kernel_launch(void* const* d_in, const int* in_sizes, int n_in,
                              void* d_out, int out_size, void* d_ws, size_t ws_size,
                              hipStream_t stream) {
    const float* x    = (const float*)d_in[0];
    const int*   eidx = (const int*)d_in[1];
    const int*   batch= (const int*)d_in[2];
    const float* W0   = (const float*)d_in[3];
    const float* b0   = (const float*)d_in[4];
    const float* g0   = (const float*)d_in[5];
    const float* be0  = (const float*)d_in[6];
    const float* Wg   = (const float*)d_in[7];
    const float* atts = (const float*)d_in[8];
    const float* attd = (const float*)d_in[9];
    const float* bg   = (const float*)d_in[10];
    const float* gg   = (const float*)d_in[11];
    const float* bgg  = (const float*)d_in[12];
    const float* Wp   = (const float*)d_in[13];
    const float* bp   = (const float*)d_in[14];
    const float* gp   = (const float*)d_in[15];
    const float* bep  = (const float*)d_in[16];

    char* ws = (char*)d_ws;
    size_t off = 0;
    auto alloc = [&](size_t bytes) {
        void* p = ws + off;
        off = (off + bytes + 255) & ~(size_t)255;
        return p;
    };
    unsigned short* h       = (unsigned short*)alloc((size_t)NPAD * 128 * 2);
    unsigned short* hh      = (unsigned short*)alloc((size_t)NN * 128 * 2);
    float*          a_s     = (float*)alloc((size_t)NN * 4 * 4);
    float*          a_d     = (float*)alloc((size_t)NN * 4 * 4);
    float*          es      = (float*)alloc((size_t)NN * 4 * 4);
    int*            offs    = (int*)alloc((size_t)(NN + 1) * 4);
    int*            cursor  = (int*)alloc((size_t)NN * 4);
    int*            counts  = (int*)alloc((size_t)NN * 4);
    int*            csr     = (int*)alloc((size_t)EPE * 4);
    int*            parts   = (int*)alloc(256 * 4);
    unsigned short* WT      = (unsigned short*)alloc(4 * 16384 * 2);
    float*          pooled  = (float*)alloc((size_t)(BGR * 128 + BGR) * 4);
    float*          cntArr  = pooled + BGR * 128;

    hipMemsetAsync(counts, 0, (size_t)NN * 4, stream);
    hipMemsetAsync(pooled, 0, (size_t)(BGR * 128 + BGR) * 4, stream);

    transpose_w<<<4, 256, 0, stream>>>(W0, Wg, WT);
    count_edges<<<(EPE + 255) / 256, 256, 0, stream>>>(eidx, counts, batch, cntArr);
    int nb = (NN + 255) / 256;
    scan1<<<nb, 256, 0, stream>>>(counts, offs, parts);
    scan2<<<1, 256, 0, stream>>>(parts, nb);
    scan3<<<nb, 256, 0, stream>>>(offs, parts, cursor);
    scatter_edges<<<(EPE + 255) / 256, 256, 0, stream>>>(eidx, cursor, csr);

    gemm_encoder<<<NPAD / 64, 256, 0, stream>>>(x, WT, b0, g0, be0, h);
    for (int l = 0; l < 3; ++l) {
        gemm_gat<<<NPAD / 64, 256, 0, stream>>>(h, WT + (l + 1) * 16384,
                                                atts + l * 128, attd + l * 128,
                                                hh, a_s, a_d, es);
        gat_aggregate<<<(NN + 3) / 4, 256, 0, stream>>>(offs, csr, a_s, a_d, es, hh, h,
                                                        bg + l * 128, gg + l * 128, bgg + l * 128,
                                                        batch, (l == 2) ? pooled : nullptr);
    }
    final_kernel<<<BGR, 128, 0, stream>>>(pooled, cntArr, Wp, bp, gp, bep, (float*)d_out);
}

// Round 8
// 610.438 us; speedup vs baseline: 1.1580x; 1.0273x over previous
//
#include <hip/hip_runtime.h>

#define NN    50000
#define EE    800000
#define EPE   850000     // EE + NN self loops
#define NPAD  50048      // multiple of 64
#define BGR   64
#define MAXCH 128        // edge chunk per node held in LDS

typedef __attribute__((ext_vector_type(8))) short bf16x8;
typedef __attribute__((ext_vector_type(4))) float f32x4;

__device__ __forceinline__ float bf2f(unsigned short u) {
    return __uint_as_float(((unsigned)u) << 16);
}
__device__ __forceinline__ unsigned short f2bf(float f) {
    unsigned u = __float_as_uint(f);
    unsigned r = (u + 0x7FFFu + ((u >> 16) & 1u)) >> 16;
    return (unsigned short)r;
}
__device__ __forceinline__ float silu(float y) { return y / (1.f + __expf(-y)); }

// ---------------- weight transpose: WT[m][col][k] = f2bf(W[m][k][col]) ----------------
__global__ void transpose_w(const float* __restrict__ W0, const float* __restrict__ Wg,
                            unsigned short* __restrict__ WT) {
    __shared__ unsigned short tile[128][129];
    int m = blockIdx.x;
    const float* src = (m == 0) ? W0 : (Wg + (m - 1) * 16384);
    unsigned short* dst = WT + m * 16384;
    for (int i = threadIdx.x; i < 16384; i += 256) tile[i >> 7][i & 127] = f2bf(src[i]);
    __syncthreads();
    for (int i = threadIdx.x; i < 16384; i += 256) {
        int c = i >> 7, k = i & 127;
        dst[i] = tile[k][c];
    }
}

// ---------------- count in-degree + per-graph node histogram ----------------
__global__ void count_edges(const int* __restrict__ eidx, int* __restrict__ counts,
                            const int* __restrict__ batch, float* __restrict__ cntArr) {
    __shared__ float lh[BGR];
    bool doHist = (blockIdx.x < 196);
    int i = blockIdx.x * 256 + threadIdx.x;
    if (doHist) {
        if (threadIdx.x < BGR) lh[threadIdx.x] = 0.f;
        __syncthreads();
    }
    if (i < EPE) {
        int d = (i < EE) ? eidx[EE + i] : (i - EE);
        atomicAdd(&counts[d], 1);
    }
    if (doHist) {
        if (i < NN) atomicAdd(&lh[batch[i]], 1.f);
        __syncthreads();
        if (threadIdx.x < BGR) {
            float v = lh[threadIdx.x];
            if (v != 0.f) atomicAdd(&cntArr[threadIdx.x], v);
        }
    }
}

// ---------------- 3-kernel exclusive scan ----------------
__global__ void scan1(const int* __restrict__ counts, int* __restrict__ offs,
                      int* __restrict__ partials) {
    __shared__ int sm[256];
    int t = threadIdx.x, i = blockIdx.x * 256 + t;
    int x = (i < NN) ? counts[i] : 0;
    sm[t] = x; __syncthreads();
    for (int d = 1; d < 256; d <<= 1) {
        int v = (t >= d) ? sm[t - d] : 0;
        __syncthreads(); sm[t] += v; __syncthreads();
    }
    if (i < NN) offs[i] = sm[t] - x;
    if (t == 255) partials[blockIdx.x] = sm[255];
}

__global__ void scan2(int* __restrict__ partials, int nb) {
    __shared__ int sm[256];
    int t = threadIdx.x;
    int x = (t < nb) ? partials[t] : 0;
    sm[t] = x; __syncthreads();
    for (int d = 1; d < 256; d <<= 1) {
        int v = (t >= d) ? sm[t - d] : 0;
        __syncthreads(); sm[t] += v; __syncthreads();
    }
    if (t < nb) partials[t] = sm[t] - x;
}

__global__ void scan3(int* __restrict__ offs, const int* __restrict__ partials,
                      int* __restrict__ cursor) {
    int i = blockIdx.x * 256 + threadIdx.x;
    if (i < NN) {
        int v = offs[i] + partials[blockIdx.x];
        offs[i] = v; cursor[i] = v;
    }
    if (i == 0) offs[NN] = EPE;
}

__global__ void scatter_edges(const int* __restrict__ eidx, int* __restrict__ cursor,
                              int* __restrict__ csr) {
    int i = blockIdx.x * 256 + threadIdx.x;
    if (i >= EPE) return;
    int s, d;
    if (i < EE) { s = eidx[i]; d = eidx[EE + i]; } else { s = i - EE; d = i - EE; }
    int pos = atomicAdd(&cursor[d], 1);
    csr[pos] = s;
}

// ---------------- encoder GEMM: h(f32) = silu(LN(x@W0 + b0)) ----------------
__global__ __launch_bounds__(256) void gemm_encoder(
    const float* __restrict__ x, const unsigned short* __restrict__ WT,
    const float* __restrict__ b0, const float* __restrict__ g0,
    const float* __restrict__ be0, float* __restrict__ h) {
    int wave = threadIdx.x >> 6, lane = threadIdx.x & 63;
    int cl = lane & 15, q = lane >> 4;
    int row0 = blockIdx.x * 64 + wave * 16;
    int rA = row0 + cl; if (rA >= NN) rA = NN - 1;
    int kq = q * 8;
    f32x4 acc[8];
#pragma unroll
    for (int t = 0; t < 8; ++t) acc[t] = (f32x4){0.f, 0.f, 0.f, 0.f};
#pragma unroll
    for (int k0 = 0; k0 < 128; k0 += 32) {
        const float* xr = x + rA * 128 + k0 + kq;
        f32x4 f0 = *(const f32x4*)(xr);
        f32x4 f1 = *(const f32x4*)(xr + 4);
        bf16x8 a;
#pragma unroll
        for (int j = 0; j < 4; ++j) {
            a[j] = (short)f2bf(f0[j]);
            a[4 + j] = (short)f2bf(f1[j]);
        }
#pragma unroll
        for (int t = 0; t < 8; ++t) {
            bf16x8 b = *(const bf16x8*)(WT + (t * 16 + cl) * 128 + k0 + kq);
            acc[t] = __builtin_amdgcn_mfma_f32_16x16x32_bf16(a, b, acc[t], 0, 0, 0);
        }
    }
    float bcol[8], gcol[8], becol[8];
#pragma unroll
    for (int t = 0; t < 8; ++t) {
        int c = t * 16 + cl;
        bcol[t] = b0[c]; gcol[t] = g0[c]; becol[t] = be0[c];
    }
#pragma unroll
    for (int r = 0; r < 4; ++r) {
        int row = row0 + q * 4 + r;
        float v[8], s = 0.f, ss = 0.f;
#pragma unroll
        for (int t = 0; t < 8; ++t) {
            v[t] = acc[t][r] + bcol[t];
            s += v[t]; ss += v[t] * v[t];
        }
#pragma unroll
        for (int m = 1; m <= 8; m <<= 1) {
            s += __shfl_xor(s, m, 64); ss += __shfl_xor(ss, m, 64);
        }
        float mu = s * (1.f / 128.f);
        float var = ss * (1.f / 128.f) - mu * mu;
        float rstd = rsqrtf(var + 1e-5f);
        if (row < NN) {
#pragma unroll
            for (int t = 0; t < 8; ++t) {
                float y = (v[t] - mu) * rstd * gcol[t] + becol[t];
                h[row * 128 + t * 16 + cl] = silu(y);
            }
        }
    }
}

// ---------------- GAT GEMM: hh = h@Wg[l] (bf16), a_s/a_d/es per node ----------------
__global__ __launch_bounds__(256) void gemm_gat(
    const float* __restrict__ h, const unsigned short* __restrict__ WT,
    const float* __restrict__ atts, const float* __restrict__ attd,
    unsigned short* __restrict__ hh, float* __restrict__ a_s, float* __restrict__ a_d,
    float* __restrict__ es) {
    int wave = threadIdx.x >> 6, lane = threadIdx.x & 63;
    int cl = lane & 15, q = lane >> 4;
    int row0 = blockIdx.x * 64 + wave * 16;
    int rA = row0 + cl; if (rA >= NN) rA = NN - 1;
    int kq = q * 8;
    f32x4 acc[8];
#pragma unroll
    for (int t = 0; t < 8; ++t) acc[t] = (f32x4){0.f, 0.f, 0.f, 0.f};
#pragma unroll
    for (int k0 = 0; k0 < 128; k0 += 32) {
        const float* hrow = h + rA * 128;
        f32x4 f0 = *(const f32x4*)(hrow + k0 + kq);
        f32x4 f1 = *(const f32x4*)(hrow + k0 + kq + 4);
        bf16x8 a;
#pragma unroll
        for (int j = 0; j < 4; ++j) {
            a[j] = (short)f2bf(f0[j]);
            a[4 + j] = (short)f2bf(f1[j]);
        }
#pragma unroll
        for (int t = 0; t < 8; ++t) {
            bf16x8 b = *(const bf16x8*)(WT + (t * 16 + cl) * 128 + k0 + kq);
            acc[t] = __builtin_amdgcn_mfma_f32_16x16x32_bf16(a, b, acc[t], 0, 0, 0);
        }
    }
#pragma unroll
    for (int r = 0; r < 4; ++r) {
        int row = row0 + q * 4 + r;
        if (row < NN) {
#pragma unroll
            for (int t = 0; t < 8; ++t)
                hh[row * 128 + t * 16 + cl] = f2bf(acc[t][r]);
        }
    }
    float as_lo[4], as_hi[4], ad_lo[4], ad_hi[4];
#pragma unroll
    for (int hd = 0; hd < 4; ++hd) {
        as_lo[hd] = atts[hd * 32 + cl];      as_hi[hd] = atts[hd * 32 + 16 + cl];
        ad_lo[hd] = attd[hd * 32 + cl];      ad_hi[hd] = attd[hd * 32 + 16 + cl];
    }
#pragma unroll
    for (int r = 0; r < 4; ++r) {
        int row = row0 + q * 4 + r;
        float ps[4], pd[4];
#pragma unroll
        for (int hd = 0; hd < 4; ++hd) {
            float v0 = acc[2 * hd][r], v1 = acc[2 * hd + 1][r];
            ps[hd] = v0 * as_lo[hd] + v1 * as_hi[hd];
            pd[hd] = v0 * ad_lo[hd] + v1 * ad_hi[hd];
        }
#pragma unroll
        for (int m = 1; m <= 8; m <<= 1) {
#pragma unroll
            for (int hd = 0; hd < 4; ++hd) {
                ps[hd] += __shfl_xor(ps[hd], m, 64);
                pd[hd] += __shfl_xor(pd[hd], m, 64);
            }
        }
        if (row < NN && cl < 4) {
            float vs = (cl == 0) ? ps[0] : (cl == 1) ? ps[1] : (cl == 2) ? ps[2] : ps[3];
            float vd = (cl == 0) ? pd[0] : (cl == 1) ? pd[1] : (cl == 2) ? pd[2] : pd[3];
            a_s[row * 4 + cl] = vs;
            a_d[row * 4 + cl] = vd;
            float e = vs + vd;                       // self-loop logit
            es[row * 4 + cl] = (e > 0.f) ? e : 0.2f * e;
        }
    }
}

// ---------------- fused aggregation (R5-proven shape): LDS weights + 4-chain ILP ------
__global__ __launch_bounds__(256) void gat_aggregate(
    const int* __restrict__ offs, const int* __restrict__ csr,
    const float* __restrict__ a_s, const float* __restrict__ a_d,
    const float* __restrict__ es, const unsigned short* __restrict__ hh,
    float* __restrict__ h,
    const float* __restrict__ bg, const float* __restrict__ gg,
    const float* __restrict__ bgg,
    const int* __restrict__ batch, float* __restrict__ pooled) {
    __shared__ f32x4 lw[4][MAXCH];
    int wv = threadIdx.x >> 6;
    int node = blockIdx.x * 4 + wv;
    int lane = threadIdx.x & 63;
    if (node >= NN) return;
    int e0 = offs[node], e1 = offs[node + 1];
    int c0 = lane * 2, hd = lane >> 4;
    // prefetch residual early (independent of the edge loop)
    float id0 = h[node * 128 + c0], id1 = h[node * 128 + c0 + 1];
    f32x4 ad4 = *(const f32x4*)(a_d + node * 4);
    f32x4 e4  = *(const f32x4*)(es  + node * 4);
    float d0 = 0.f, d1 = 0.f, d2 = 0.f, d3 = 0.f;
    float x0 = 0.f, y0 = 0.f, x1 = 0.f, y1 = 0.f;
    float x2 = 0.f, y2 = 0.f, x3 = 0.f, y3 = 0.f;
    for (int base = e0; base < e1; base += MAXCH) {
        int cend = min(e1, base + MAXCH);
        // phase A: lanes compute softmax weights for this chunk (all 4 heads)
        for (int e = base + lane; e < cend; e += 64) {
            int s = csr[e];
            f32x4 as = *(const f32x4*)(a_s + s * 4);
            f32x4 o;
#pragma unroll
            for (int k = 0; k < 4; ++k) {
                float qq = as[k] + ad4[k];
                qq = (qq > 0.f) ? qq : 0.2f * qq;
                o[k] = __expf(qq - e4[k]);
            }
            lw[wv][e - base] = o;
        }
        asm volatile("s_waitcnt lgkmcnt(0)" ::: "memory");
        // phase B: serial weighted accumulation over the chunk (4 chains)
        int e = base;
        for (; e + 4 <= cend; e += 4) {
            int s0 = csr[e], s1 = csr[e + 1], s2 = csr[e + 2], s3 = csr[e + 3];
            float w0 = lw[wv][e - base + 0][hd];
            float w1 = lw[wv][e - base + 1][hd];
            float w2 = lw[wv][e - base + 2][hd];
            float w3 = lw[wv][e - base + 3][hd];
            unsigned v0 = *(const unsigned*)(hh + s0 * 128 + c0);
            unsigned v1 = *(const unsigned*)(hh + s1 * 128 + c0);
            unsigned v2 = *(const unsigned*)(hh + s2 * 128 + c0);
            unsigned v3 = *(const unsigned*)(hh + s3 * 128 + c0);
            d0 += w0; x0 += w0 * bf2f((unsigned short)(v0 & 0xFFFFu)); y0 += w0 * bf2f((unsigned short)(v0 >> 16));
            d1 += w1; x1 += w1 * bf2f((unsigned short)(v1 & 0xFFFFu)); y1 += w1 * bf2f((unsigned short)(v1 >> 16));
            d2 += w2; x2 += w2 * bf2f((unsigned short)(v2 & 0xFFFFu)); y2 += w2 * bf2f((unsigned short)(v2 >> 16));
            d3 += w3; x3 += w3 * bf2f((unsigned short)(v3 & 0xFFFFu)); y3 += w3 * bf2f((unsigned short)(v3 >> 16));
        }
        for (; e < cend; ++e) {
            int s0 = csr[e];
            float w0 = lw[wv][e - base][hd];
            unsigned v0 = *(const unsigned*)(hh + s0 * 128 + c0);
            d0 += w0; x0 += w0 * bf2f((unsigned short)(v0 & 0xFFFFu)); y0 += w0 * bf2f((unsigned short)(v0 >> 16));
        }
        if (cend < e1)
            asm volatile("s_waitcnt lgkmcnt(0)" ::: "memory");
    }
    float den = (d0 + d1) + (d2 + d3);
    float X = (x0 + x1) + (x2 + x3);
    float Y = (y0 + y1) + (y2 + y3);
    float inv = 1.f / den;
    float o0 = X * inv + bg[c0];
    float o1 = Y * inv + bg[c0 + 1];
    float s = o0 + o1, ss = o0 * o0 + o1 * o1;
#pragma unroll
    for (int m = 1; m <= 32; m <<= 1) {
        s += __shfl_xor(s, m, 64); ss += __shfl_xor(ss, m, 64);
    }
    float mu = s * (1.f / 128.f);
    float var = ss * (1.f / 128.f) - mu * mu;
    float rstd = rsqrtf(var + 1e-5f);
    float yy0 = (o0 - mu) * rstd * gg[c0] + bgg[c0];
    float yy1 = (o1 - mu) * rstd * gg[c0 + 1] + bgg[c0 + 1];
    float r0 = silu(yy0) + id0;
    float r1 = silu(yy1) + id1;
    h[node * 128 + c0]     = r0;
    h[node * 128 + c0 + 1] = r1;
    if (pooled) {
        int g = batch[node];
        atomicAdd(&pooled[g * 128 + c0], r0);
        atomicAdd(&pooled[g * 128 + c0 + 1], r1);
    }
}

// ---------------- head: silu(LN(pooled/cnt @ Wp + bp)) -> f32 out ----------------
__global__ void final_kernel(const float* __restrict__ pooled, const float* __restrict__ cntArr,
                             const float* __restrict__ Wp, const float* __restrict__ bp,
                             const float* __restrict__ gp, const float* __restrict__ bep,
                             float* __restrict__ out) {
    __shared__ float p[128];
    __shared__ float red[128];
    int g = blockIdx.x, c = threadIdx.x;
    float cnt = cntArr[g]; if (cnt < 1.f) cnt = 1.f;
    p[c] = pooled[g * 128 + c] / cnt;
    __syncthreads();
    float acc = bp[c];
    for (int k = 0; k < 128; ++k) acc += p[k] * Wp[k * 128 + c];
    red[c] = acc;
    __syncthreads();
    if (c < 64) {
        float s = red[c] + red[c + 64];
#pragma unroll
        for (int m = 1; m <= 32; m <<= 1) s += __shfl_xor(s, m, 64);
        if (c == 0) red[0] = s;
    }
    __syncthreads();
    float mu = red[0] * (1.f / 128.f);
    __syncthreads();
    float dv = acc - mu;
    red[c] = dv * dv;
    __syncthreads();
    if (c < 64) {
        float s = red[c] + red[c + 64];
#pragma unroll
        for (int m = 1; m <= 32; m <<= 1) s += __shfl_xor(s, m, 64);
        if (c == 0) red[0] = s;
    }
    __syncthreads();
    float var = red[0] * (1.f / 128.f);
    float rstd = rsqrtf(var + 1e-5f);
    float y = dv * rstd * gp[c] + bep[c];
    out[g * 128 + c] = silu(y);
}

extern "C" void kernel_launch(void* const* d_in, const int* in_sizes, int n_in,
                              void* d_out, int out_size, void* d_ws, size_t ws_size,
                              hipStream_t stream) {
    const float* x    = (const float*)d_in[0];
    const int*   eidx = (const int*)d_in[1];
    const int*   batch= (const int*)d_in[2];
    const float* W0   = (const float*)d_in[3];
    const float* b0   = (const float*)d_in[4];
    const float* g0   = (const float*)d_in[5];
    const float* be0  = (const float*)d_in[6];
    const float* Wg   = (const float*)d_in[7];
    const float* atts = (const float*)d_in[8];
    const float* attd = (const float*)d_in[9];
    const float* bg   = (const float*)d_in[10];
    const float* gg   = (const float*)d_in[11];
    const float* bgg  = (const float*)d_in[12];
    const float* Wp   = (const float*)d_in[13];
    const float* bp   = (const float*)d_in[14];
    const float* gp   = (const float*)d_in[15];
    const float* bep  = (const float*)d_in[16];

    char* ws = (char*)d_ws;
    size_t off = 0;
    auto alloc = [&](size_t bytes) {
        void* p = ws + off;
        off = (off + bytes + 255) & ~(size_t)255;
        return p;
    };
    float*          h       = (float*)alloc((size_t)NPAD * 128 * 4);
    unsigned short* hh      = (unsigned short*)alloc((size_t)NN * 128 * 2);
    float*          a_s     = (float*)alloc((size_t)NN * 4 * 4);
    float*          a_d     = (float*)alloc((size_t)NN * 4 * 4);
    float*          es      = (float*)alloc((size_t)NN * 4 * 4);
    int*            offs    = (int*)alloc((size_t)(NN + 1) * 4);
    int*            cursor  = (int*)alloc((size_t)NN * 4);
    int*            counts  = (int*)alloc((size_t)NN * 4);
    int*            csr     = (int*)alloc((size_t)EPE * 4);
    int*            parts   = (int*)alloc(256 * 4);
    unsigned short* WT      = (unsigned short*)alloc(4 * 16384 * 2);
    float*          pooled  = (float*)alloc((size_t)(BGR * 128 + BGR) * 4);
    float*          cntArr  = pooled + BGR * 128;

    hipMemsetAsync(counts, 0, (size_t)NN * 4, stream);
    hipMemsetAsync(pooled, 0, (size_t)(BGR * 128 + BGR) * 4, stream);

    transpose_w<<<4, 256, 0, stream>>>(W0, Wg, WT);
    count_edges<<<(EPE + 255) / 256, 256, 0, stream>>>(eidx, counts, batch, cntArr);
    int nb = (NN + 255) / 256;
    scan1<<<nb, 256, 0, stream>>>(counts, offs, parts);
    scan2<<<1, 256, 0, stream>>>(parts, nb);
    scan3<<<nb, 256, 0, stream>>>(offs, parts, cursor);
    scatter_edges<<<(EPE + 255) / 256, 256, 0, stream>>>(eidx, cursor, csr);

    gemm_encoder<<<NPAD / 64, 256, 0, stream>>>(x, WT, b0, g0, be0, h);
    for (int l = 0; l < 3; ++l) {
        gemm_gat<<<NPAD / 64, 256, 0, stream>>>(h, WT + (l + 1) * 16384,
                                                atts + l * 128, attd + l * 128,
                                                hh, a_s, a_d, es);
        gat_aggregate<<<(NN + 3) / 4, 256, 0, stream>>>(offs, csr, a_s, a_d, es, hh, h,
                                                        bg + l * 128, gg + l * 128, bgg + l * 128,
                                                        batch, (l == 2) ? pooled : nullptr);
    }
    final_kernel<<<BGR, 128, 0, stream>>>(pooled, cntArr, Wp, bp, gp, bep, (float*)d_out);
}

// Round 9
// 478.545 us; speedup vs baseline: 1.4771x; 1.2756x over previous
//
#include <hip/hip_runtime.h>

#define NN    50000
#define EE    800000
#define EPE   850000     // EE + NN self loops
#define NPAD  50048      // multiple of 64
#define BGR   64
#define MAXCH 128        // edge chunk per node held in LDS

typedef __attribute__((ext_vector_type(8))) short bf16x8;
typedef __attribute__((ext_vector_type(4))) float f32x4;

__device__ __forceinline__ float bf2f(unsigned short u) {
    return __uint_as_float(((unsigned)u) << 16);
}
__device__ __forceinline__ unsigned short f2bf(float f) {
    unsigned u = __float_as_uint(f);
    unsigned r = (u + 0x7FFFu + ((u >> 16) & 1u)) >> 16;
    return (unsigned short)r;
}
__device__ __forceinline__ float silu(float y) { return y / (1.f + __expf(-y)); }

// ---------------- weight transpose: WT[m][col][k] = f2bf(W[m][k][col]) ----------------
__global__ void transpose_w(const float* __restrict__ W0, const float* __restrict__ Wg,
                            unsigned short* __restrict__ WT) {
    __shared__ unsigned short tile[128][129];
    int m = blockIdx.x;
    const float* src = (m == 0) ? W0 : (Wg + (m - 1) * 16384);
    unsigned short* dst = WT + m * 16384;
    for (int i = threadIdx.x; i < 16384; i += 256) tile[i >> 7][i & 127] = f2bf(src[i]);
    __syncthreads();
    for (int i = threadIdx.x; i < 16384; i += 256) {
        int c = i >> 7, k = i & 127;
        dst[i] = tile[k][c];
    }
}

// ---------------- count in-degree + per-graph node histogram ----------------
__global__ void count_edges(const int* __restrict__ eidx, int* __restrict__ counts,
                            const int* __restrict__ batch, float* __restrict__ cntArr) {
    __shared__ float lh[BGR];
    bool doHist = (blockIdx.x < 196);
    int i = blockIdx.x * 256 + threadIdx.x;
    if (doHist) {
        if (threadIdx.x < BGR) lh[threadIdx.x] = 0.f;
        __syncthreads();
    }
    if (i < EPE) {
        int d = (i < EE) ? eidx[EE + i] : (i - EE);
        atomicAdd(&counts[d], 1);
    }
    if (doHist) {
        if (i < NN) atomicAdd(&lh[batch[i]], 1.f);
        __syncthreads();
        if (threadIdx.x < BGR) {
            float v = lh[threadIdx.x];
            if (v != 0.f) atomicAdd(&cntArr[threadIdx.x], v);
        }
    }
}

// ---------------- 3-kernel exclusive scan ----------------
__global__ void scan1(const int* __restrict__ counts, int* __restrict__ offs,
                      int* __restrict__ partials) {
    __shared__ int sm[256];
    int t = threadIdx.x, i = blockIdx.x * 256 + t;
    int x = (i < NN) ? counts[i] : 0;
    sm[t] = x; __syncthreads();
    for (int d = 1; d < 256; d <<= 1) {
        int v = (t >= d) ? sm[t - d] : 0;
        __syncthreads(); sm[t] += v; __syncthreads();
    }
    if (i < NN) offs[i] = sm[t] - x;
    if (t == 255) partials[blockIdx.x] = sm[255];
}

__global__ void scan2(int* __restrict__ partials, int nb) {
    __shared__ int sm[256];
    int t = threadIdx.x;
    int x = (t < nb) ? partials[t] : 0;
    sm[t] = x; __syncthreads();
    for (int d = 1; d < 256; d <<= 1) {
        int v = (t >= d) ? sm[t - d] : 0;
        __syncthreads(); sm[t] += v; __syncthreads();
    }
    if (t < nb) partials[t] = sm[t] - x;
}

__global__ void scan3(int* __restrict__ offs, const int* __restrict__ partials,
                      int* __restrict__ cursor) {
    int i = blockIdx.x * 256 + threadIdx.x;
    if (i < NN) {
        int v = offs[i] + partials[blockIdx.x];
        offs[i] = v; cursor[i] = v;
    }
    if (i == 0) offs[NN] = EPE;
}

__global__ void scatter_edges(const int* __restrict__ eidx, int* __restrict__ cursor,
                              int* __restrict__ csr) {
    int i = blockIdx.x * 256 + threadIdx.x;
    if (i >= EPE) return;
    int s, d;
    if (i < EE) { s = eidx[i]; d = eidx[EE + i]; } else { s = i - EE; d = i - EE; }
    int pos = atomicAdd(&cursor[d], 1);
    csr[pos] = s;
}

// ---------------- encoder GEMM: h(f32) = silu(LN(x@W0 + b0)) ----------------
__global__ __launch_bounds__(256) void gemm_encoder(
    const float* __restrict__ x, const unsigned short* __restrict__ WT,
    const float* __restrict__ b0, const float* __restrict__ g0,
    const float* __restrict__ be0, float* __restrict__ h) {
    int wave = threadIdx.x >> 6, lane = threadIdx.x & 63;
    int cl = lane & 15, q = lane >> 4;
    int row0 = blockIdx.x * 64 + wave * 16;
    int rA = row0 + cl; if (rA >= NN) rA = NN - 1;
    int kq = q * 8;
    f32x4 acc[8];
#pragma unroll
    for (int t = 0; t < 8; ++t) acc[t] = (f32x4){0.f, 0.f, 0.f, 0.f};
#pragma unroll
    for (int k0 = 0; k0 < 128; k0 += 32) {
        const float* xr = x + rA * 128 + k0 + kq;
        f32x4 f0 = *(const f32x4*)(xr);
        f32x4 f1 = *(const f32x4*)(xr + 4);
        bf16x8 a;
#pragma unroll
        for (int j = 0; j < 4; ++j) {
            a[j] = (short)f2bf(f0[j]);
            a[4 + j] = (short)f2bf(f1[j]);
        }
#pragma unroll
        for (int t = 0; t < 8; ++t) {
            bf16x8 b = *(const bf16x8*)(WT + (t * 16 + cl) * 128 + k0 + kq);
            acc[t] = __builtin_amdgcn_mfma_f32_16x16x32_bf16(a, b, acc[t], 0, 0, 0);
        }
    }
    float bcol[8], gcol[8], becol[8];
#pragma unroll
    for (int t = 0; t < 8; ++t) {
        int c = t * 16 + cl;
        bcol[t] = b0[c]; gcol[t] = g0[c]; becol[t] = be0[c];
    }
#pragma unroll
    for (int r = 0; r < 4; ++r) {
        int row = row0 + q * 4 + r;
        float v[8], s = 0.f, ss = 0.f;
#pragma unroll
        for (int t = 0; t < 8; ++t) {
            v[t] = acc[t][r] + bcol[t];
            s += v[t]; ss += v[t] * v[t];
        }
#pragma unroll
        for (int m = 1; m <= 8; m <<= 1) {
            s += __shfl_xor(s, m, 64); ss += __shfl_xor(ss, m, 64);
        }
        float mu = s * (1.f / 128.f);
        float var = ss * (1.f / 128.f) - mu * mu;
        float rstd = rsqrtf(var + 1e-5f);
        if (row < NN) {
#pragma unroll
            for (int t = 0; t < 8; ++t) {
                float y = (v[t] - mu) * rstd * gcol[t] + becol[t];
                h[row * 128 + t * 16 + cl] = silu(y);
            }
        }
    }
}

// ---------------- GAT GEMM: hh = h@Wg[l] (bf16), a_s/a_d/es per node ----------------
__global__ __launch_bounds__(256) void gemm_gat(
    const float* __restrict__ h, const unsigned short* __restrict__ WT,
    const float* __restrict__ atts, const float* __restrict__ attd,
    unsigned short* __restrict__ hh, float* __restrict__ a_s, float* __restrict__ a_d,
    float* __restrict__ es) {
    int wave = threadIdx.x >> 6, lane = threadIdx.x & 63;
    int cl = lane & 15, q = lane >> 4;
    int row0 = blockIdx.x * 64 + wave * 16;
    int rA = row0 + cl; if (rA >= NN) rA = NN - 1;
    int kq = q * 8;
    f32x4 acc[8];
#pragma unroll
    for (int t = 0; t < 8; ++t) acc[t] = (f32x4){0.f, 0.f, 0.f, 0.f};
#pragma unroll
    for (int k0 = 0; k0 < 128; k0 += 32) {
        const float* hrow = h + rA * 128;
        f32x4 f0 = *(const f32x4*)(hrow + k0 + kq);
        f32x4 f1 = *(const f32x4*)(hrow + k0 + kq + 4);
        bf16x8 a;
#pragma unroll
        for (int j = 0; j < 4; ++j) {
            a[j] = (short)f2bf(f0[j]);
            a[4 + j] = (short)f2bf(f1[j]);
        }
#pragma unroll
        for (int t = 0; t < 8; ++t) {
            bf16x8 b = *(const bf16x8*)(WT + (t * 16 + cl) * 128 + k0 + kq);
            acc[t] = __builtin_amdgcn_mfma_f32_16x16x32_bf16(a, b, acc[t], 0, 0, 0);
        }
    }
#pragma unroll
    for (int r = 0; r < 4; ++r) {
        int row = row0 + q * 4 + r;
        if (row < NN) {
#pragma unroll
            for (int t = 0; t < 8; ++t)
                hh[row * 128 + t * 16 + cl] = f2bf(acc[t][r]);
        }
    }
    float as_lo[4], as_hi[4], ad_lo[4], ad_hi[4];
#pragma unroll
    for (int hd = 0; hd < 4; ++hd) {
        as_lo[hd] = atts[hd * 32 + cl];      as_hi[hd] = atts[hd * 32 + 16 + cl];
        ad_lo[hd] = attd[hd * 32 + cl];      ad_hi[hd] = attd[hd * 32 + 16 + cl];
    }
#pragma unroll
    for (int r = 0; r < 4; ++r) {
        int row = row0 + q * 4 + r;
        float ps[4], pd[4];
#pragma unroll
        for (int hd = 0; hd < 4; ++hd) {
            float v0 = acc[2 * hd][r], v1 = acc[2 * hd + 1][r];
            ps[hd] = v0 * as_lo[hd] + v1 * as_hi[hd];
            pd[hd] = v0 * ad_lo[hd] + v1 * ad_hi[hd];
        }
#pragma unroll
        for (int m = 1; m <= 8; m <<= 1) {
#pragma unroll
            for (int hd = 0; hd < 4; ++hd) {
                ps[hd] += __shfl_xor(ps[hd], m, 64);
                pd[hd] += __shfl_xor(pd[hd], m, 64);
            }
        }
        if (row < NN && cl < 4) {
            float vs = (cl == 0) ? ps[0] : (cl == 1) ? ps[1] : (cl == 2) ? ps[2] : ps[3];
            float vd = (cl == 0) ? pd[0] : (cl == 1) ? pd[1] : (cl == 2) ? pd[2] : pd[3];
            a_s[row * 4 + cl] = vs;
            a_d[row * 4 + cl] = vd;
            float e = vs + vd;                       // self-loop logit
            es[row * 4 + cl] = (e > 0.f) ? e : 0.2f * e;
        }
    }
}

// ---------------- fused aggregation (exact R5 shape): LDS weights + 4-chain ILP -------
__global__ __launch_bounds__(256) void gat_aggregate(
    const int* __restrict__ offs, const int* __restrict__ csr,
    const float* __restrict__ a_s, const float* __restrict__ a_d,
    const float* __restrict__ es, const unsigned short* __restrict__ hh,
    float* __restrict__ h,
    const float* __restrict__ bg, const float* __restrict__ gg,
    const float* __restrict__ bgg) {
    __shared__ f32x4 lw[4][MAXCH];
    int wv = threadIdx.x >> 6;
    int node = blockIdx.x * 4 + wv;
    int lane = threadIdx.x & 63;
    if (node >= NN) return;
    int e0 = offs[node], e1 = offs[node + 1];
    int c0 = lane * 2, hd = lane >> 4;
    f32x4 ad4 = *(const f32x4*)(a_d + node * 4);
    f32x4 e4  = *(const f32x4*)(es  + node * 4);
    float d0 = 0.f, d1 = 0.f, d2 = 0.f, d3 = 0.f;
    float x0 = 0.f, y0 = 0.f, x1 = 0.f, y1 = 0.f;
    float x2 = 0.f, y2 = 0.f, x3 = 0.f, y3 = 0.f;
    for (int base = e0; base < e1; base += MAXCH) {
        int cend = min(e1, base + MAXCH);
        // phase A: lanes compute softmax weights for this chunk (all 4 heads)
        for (int e = base + lane; e < cend; e += 64) {
            int s = csr[e];
            f32x4 as = *(const f32x4*)(a_s + s * 4);
            f32x4 o;
#pragma unroll
            for (int k = 0; k < 4; ++k) {
                float qq = as[k] + ad4[k];
                qq = (qq > 0.f) ? qq : 0.2f * qq;
                o[k] = __expf(qq - e4[k]);
            }
            lw[wv][e - base] = o;
        }
        asm volatile("s_waitcnt lgkmcnt(0)" ::: "memory");
        // phase B: serial weighted accumulation over the chunk (4 chains)
        int e = base;
        for (; e + 4 <= cend; e += 4) {
            int s0 = csr[e], s1 = csr[e + 1], s2 = csr[e + 2], s3 = csr[e + 3];
            float w0 = lw[wv][e - base + 0][hd];
            float w1 = lw[wv][e - base + 1][hd];
            float w2 = lw[wv][e - base + 2][hd];
            float w3 = lw[wv][e - base + 3][hd];
            unsigned v0 = *(const unsigned*)(hh + s0 * 128 + c0);
            unsigned v1 = *(const unsigned*)(hh + s1 * 128 + c0);
            unsigned v2 = *(const unsigned*)(hh + s2 * 128 + c0);
            unsigned v3 = *(const unsigned*)(hh + s3 * 128 + c0);
            d0 += w0; x0 += w0 * bf2f((unsigned short)(v0 & 0xFFFFu)); y0 += w0 * bf2f((unsigned short)(v0 >> 16));
            d1 += w1; x1 += w1 * bf2f((unsigned short)(v1 & 0xFFFFu)); y1 += w1 * bf2f((unsigned short)(v1 >> 16));
            d2 += w2; x2 += w2 * bf2f((unsigned short)(v2 & 0xFFFFu)); y2 += w2 * bf2f((unsigned short)(v2 >> 16));
            d3 += w3; x3 += w3 * bf2f((unsigned short)(v3 & 0xFFFFu)); y3 += w3 * bf2f((unsigned short)(v3 >> 16));
        }
        for (; e < cend; ++e) {
            int s0 = csr[e];
            float w0 = lw[wv][e - base][hd];
            unsigned v0 = *(const unsigned*)(hh + s0 * 128 + c0);
            d0 += w0; x0 += w0 * bf2f((unsigned short)(v0 & 0xFFFFu)); y0 += w0 * bf2f((unsigned short)(v0 >> 16));
        }
        if (cend < e1)
            asm volatile("s_waitcnt lgkmcnt(0)" ::: "memory");
    }
    float den = (d0 + d1) + (d2 + d3);
    float X = (x0 + x1) + (x2 + x3);
    float Y = (y0 + y1) + (y2 + y3);
    float inv = 1.f / den;
    float o0 = X * inv + bg[c0];
    float o1 = Y * inv + bg[c0 + 1];
    float s = o0 + o1, ss = o0 * o0 + o1 * o1;
#pragma unroll
    for (int m = 1; m <= 32; m <<= 1) {
        s += __shfl_xor(s, m, 64); ss += __shfl_xor(ss, m, 64);
    }
    float mu = s * (1.f / 128.f);
    float var = ss * (1.f / 128.f) - mu * mu;
    float rstd = rsqrtf(var + 1e-5f);
    float yy0 = (o0 - mu) * rstd * gg[c0] + bgg[c0];
    float yy1 = (o1 - mu) * rstd * gg[c0 + 1] + bgg[c0 + 1];
    float id0 = h[node * 128 + c0], id1 = h[node * 128 + c0 + 1];
    h[node * 128 + c0]     = silu(yy0) + id0;
    h[node * 128 + c0 + 1] = silu(yy1) + id1;
}

// ---------------- mean pool per graph (batch sorted); counts come from hist ----------
__global__ void pool_kernel(const float* __restrict__ h, const int* __restrict__ batch,
                            float* __restrict__ pooled) {
    int c = threadIdx.x;
    int r0 = blockIdx.x * 64;
    int rend = r0 + 64; if (rend > NN) rend = NN;
    int cur = batch[r0];
    float acc = 0.f;
    for (int r = r0; r < rend; ++r) {
        int b = batch[r];
        float v = h[r * 128 + c];
        if (b != cur) {
            atomicAdd(&pooled[cur * 128 + c], acc);
            acc = 0.f; cur = b;
        }
        acc += v;
    }
    atomicAdd(&pooled[cur * 128 + c], acc);
}

// ---------------- head: silu(LN(pooled/cnt @ Wp + bp)) -> f32 out ----------------
__global__ void final_kernel(const float* __restrict__ pooled, const float* __restrict__ cntArr,
                             const float* __restrict__ Wp, const float* __restrict__ bp,
                             const float* __restrict__ gp, const float* __restrict__ bep,
                             float* __restrict__ out) {
    __shared__ float p[128];
    __shared__ float red[128];
    int g = blockIdx.x, c = threadIdx.x;
    float cnt = cntArr[g]; if (cnt < 1.f) cnt = 1.f;
    p[c] = pooled[g * 128 + c] / cnt;
    __syncthreads();
    float acc = bp[c];
    for (int k = 0; k < 128; ++k) acc += p[k] * Wp[k * 128 + c];
    red[c] = acc;
    __syncthreads();
    if (c < 64) {
        float s = red[c] + red[c + 64];
#pragma unroll
        for (int m = 1; m <= 32; m <<= 1) s += __shfl_xor(s, m, 64);
        if (c == 0) red[0] = s;
    }
    __syncthreads();
    float mu = red[0] * (1.f / 128.f);
    __syncthreads();
    float dv = acc - mu;
    red[c] = dv * dv;
    __syncthreads();
    if (c < 64) {
        float s = red[c] + red[c + 64];
#pragma unroll
        for (int m = 1; m <= 32; m <<= 1) s += __shfl_xor(s, m, 64);
        if (c == 0) red[0] = s;
    }
    __syncthreads();
    float var = red[0] * (1.f / 128.f);
    float rstd = rsqrtf(var + 1e-5f);
    float y = dv * rstd * gp[c] + bep[c];
    out[g * 128 + c] = silu(y);
}

extern "C" void kernel_launch(void* const* d_in, const int* in_sizes, int n_in,
                              void* d_out, int out_size, void* d_ws, size_t ws_size,
                              hipStream_t stream) {
    const float* x    = (const float*)d_in[0];
    const int*   eidx = (const int*)d_in[1];
    const int*   batch= (const int*)d_in[2];
    const float* W0   = (const float*)d_in[3];
    const float* b0   = (const float*)d_in[4];
    const float* g0   = (const float*)d_in[5];
    const float* be0  = (const float*)d_in[6];
    const float* Wg   = (const float*)d_in[7];
    const float* atts = (const float*)d_in[8];
    const float* attd = (const float*)d_in[9];
    const float* bg   = (const float*)d_in[10];
    const float* gg   = (const float*)d_in[11];
    const float* bgg  = (const float*)d_in[12];
    const float* Wp   = (const float*)d_in[13];
    const float* bp   = (const float*)d_in[14];
    const float* gp   = (const float*)d_in[15];
    const float* bep  = (const float*)d_in[16];

    char* ws = (char*)d_ws;
    size_t off = 0;
    auto alloc = [&](size_t bytes) {
        void* p = ws + off;
        off = (off + bytes + 255) & ~(size_t)255;
        return p;
    };
    float*          h       = (float*)alloc((size_t)NPAD * 128 * 4);
    unsigned short* hh      = (unsigned short*)alloc((size_t)NN * 128 * 2);
    float*          a_s     = (float*)alloc((size_t)NN * 4 * 4);
    float*          a_d     = (float*)alloc((size_t)NN * 4 * 4);
    float*          es      = (float*)alloc((size_t)NN * 4 * 4);
    int*            offs    = (int*)alloc((size_t)(NN + 1) * 4);
    int*            cursor  = (int*)alloc((size_t)NN * 4);
    int*            counts  = (int*)alloc((size_t)NN * 4);
    int*            csr     = (int*)alloc((size_t)EPE * 4);
    int*            parts   = (int*)alloc(256 * 4);
    unsigned short* WT      = (unsigned short*)alloc(4 * 16384 * 2);
    float*          pooled  = (float*)alloc((size_t)(BGR * 128 + BGR) * 4);
    float*          cntArr  = pooled + BGR * 128;

    hipMemsetAsync(counts, 0, (size_t)NN * 4, stream);
    hipMemsetAsync(pooled, 0, (size_t)(BGR * 128 + BGR) * 4, stream);

    transpose_w<<<4, 256, 0, stream>>>(W0, Wg, WT);
    count_edges<<<(EPE + 255) / 256, 256, 0, stream>>>(eidx, counts, batch, cntArr);
    int nb = (NN + 255) / 256;
    scan1<<<nb, 256, 0, stream>>>(counts, offs, parts);
    scan2<<<1, 256, 0, stream>>>(parts, nb);
    scan3<<<nb, 256, 0, stream>>>(offs, parts, cursor);
    scatter_edges<<<(EPE + 255) / 256, 256, 0, stream>>>(eidx, cursor, csr);

    gemm_encoder<<<NPAD / 64, 256, 0, stream>>>(x, WT, b0, g0, be0, h);
    for (int l = 0; l < 3; ++l) {
        gemm_gat<<<NPAD / 64, 256, 0, stream>>>(h, WT + (l + 1) * 16384,
                                                atts + l * 128, attd + l * 128,
                                                hh, a_s, a_d, es);
        gat_aggregate<<<(NN + 3) / 4, 256, 0, stream>>>(offs, csr, a_s, a_d, es, hh, h,
                                                        bg + l * 128, gg + l * 128,
                                                        bgg + l * 128);
    }
    pool_kernel<<<(NN + 63) / 64, 128, 0, stream>>>(h, batch, pooled);
    final_kernel<<<BGR, 128, 0, stream>>>(pooled, cntArr, Wp, bp, gp, bep, (float*)d_out);
}

// Round 10
// 464.214 us; speedup vs baseline: 1.5227x; 1.0309x over previous
//
#include <hip/hip_runtime.h>

#define NN    50000
#define EE    800000
#define EPE   850000     // EE + NN self loops
#define NPAD  50048      // multiple of 64
#define BGR   64
#define MAXCH 128        // edge chunk per node held in LDS (aggregate)
#define NB    98         // buckets of 512 nodes
#define CHUNK 4096       // edges per binning block
#define NBLK  208        // ceil(EPE / CHUNK)
#define BCAP  12288      // per-bucket LDS capacity in build_csr (mean ~8700, 36-sigma margin)

typedef __attribute__((ext_vector_type(8))) short bf16x8;
typedef __attribute__((ext_vector_type(4))) float f32x4;

__device__ __forceinline__ float bf2f(unsigned short u) {
    return __uint_as_float(((unsigned)u) << 16);
}
__device__ __forceinline__ unsigned short f2bf(float f) {
    unsigned u = __float_as_uint(f);
    unsigned r = (u + 0x7FFFu + ((u >> 16) & 1u)) >> 16;
    return (unsigned short)r;
}
__device__ __forceinline__ float silu(float y) { return y / (1.f + __expf(-y)); }

// ---------------- weight transpose: WT[m][col][k] = f2bf(W[m][k][col]) ----------------
__global__ void transpose_w(const float* __restrict__ W0, const float* __restrict__ Wg,
                            unsigned short* __restrict__ WT) {
    __shared__ unsigned short tile[128][129];
    int m = blockIdx.x;
    const float* src = (m == 0) ? W0 : (Wg + (m - 1) * 16384);
    unsigned short* dst = WT + m * 16384;
    for (int i = threadIdx.x; i < 16384; i += 256) tile[i >> 7][i & 127] = f2bf(src[i]);
    __syncthreads();
    for (int i = threadIdx.x; i < 16384; i += 256) {
        int c = i >> 7, k = i & 127;
        dst[i] = tile[k][c];
    }
}

// ---------------- count in-degree + per-graph node histogram ----------------
__global__ void count_edges(const int* __restrict__ eidx, int* __restrict__ counts,
                            const int* __restrict__ batch, float* __restrict__ cntArr) {
    __shared__ float lh[BGR];
    bool doHist = (blockIdx.x < 196);
    int i = blockIdx.x * 256 + threadIdx.x;
    if (doHist) {
        if (threadIdx.x < BGR) lh[threadIdx.x] = 0.f;
        __syncthreads();
    }
    if (i < EPE) {
        int d = (i < EE) ? eidx[EE + i] : (i - EE);
        atomicAdd(&counts[d], 1);
    }
    if (doHist) {
        if (i < NN) atomicAdd(&lh[batch[i]], 1.f);
        __syncthreads();
        if (threadIdx.x < BGR) {
            float v = lh[threadIdx.x];
            if (v != 0.f) atomicAdd(&cntArr[threadIdx.x], v);
        }
    }
}

// ---------------- 3-kernel exclusive scan over per-node counts ----------------
__global__ void scan1(const int* __restrict__ counts, int* __restrict__ offs,
                      int* __restrict__ partials) {
    __shared__ int sm[256];
    int t = threadIdx.x, i = blockIdx.x * 256 + t;
    int x = (i < NN) ? counts[i] : 0;
    sm[t] = x; __syncthreads();
    for (int d = 1; d < 256; d <<= 1) {
        int v = (t >= d) ? sm[t - d] : 0;
        __syncthreads(); sm[t] += v; __syncthreads();
    }
    if (i < NN) offs[i] = sm[t] - x;
    if (t == 255) partials[blockIdx.x] = sm[255];
}

__global__ void scan2(int* __restrict__ partials, int nb) {
    __shared__ int sm[256];
    int t = threadIdx.x;
    int x = (t < nb) ? partials[t] : 0;
    sm[t] = x; __syncthreads();
    for (int d = 1; d < 256; d <<= 1) {
        int v = (t >= d) ? sm[t - d] : 0;
        __syncthreads(); sm[t] += v; __syncthreads();
    }
    if (t < nb) partials[t] = sm[t] - x;
}

__global__ void scan3(int* __restrict__ offs, const int* __restrict__ partials) {
    int i = blockIdx.x * 256 + threadIdx.x;
    if (i < NN) offs[i] += partials[blockIdx.x];
    if (i == 0) offs[NN] = EPE;
}

// ---------------- bucketed CSR build, phase 0: per-block bucket histograms ----------
__global__ __launch_bounds__(256) void bucket_hist(const int* __restrict__ eidx,
                                                   int* __restrict__ hist_blk) {
    __shared__ int lh[NB];
    for (int t = threadIdx.x; t < NB; t += 256) lh[t] = 0;
    __syncthreads();
    int base = blockIdx.x * CHUNK;
#pragma unroll
    for (int j = 0; j < CHUNK / 256; ++j) {
        int i = base + j * 256 + threadIdx.x;
        if (i < EPE) {
            int d = (i < EE) ? eidx[EE + i] : (i - EE);
            atomicAdd(&lh[d >> 9], 1);
        }
    }
    __syncthreads();
    for (int t = threadIdx.x; t < NB; t += 256)
        hist_blk[blockIdx.x * NB + t] = lh[t];
}

// ---------------- phase 1: 2D exclusive scan -> per-block per-bucket offsets ----------
__global__ void scan_buckets(const int* __restrict__ hist_blk, int* __restrict__ blkOfs,
                             int* __restrict__ bucketBase) {
    __shared__ int tot[NB];
    __shared__ int base[NB];
    int t = threadIdx.x;
    if (t < NB) {
        int s = 0;
        for (int k = 0; k < NBLK; ++k) s += hist_blk[k * NB + t];
        tot[t] = s;
    }
    __syncthreads();
    if (t == 0) {
        int run = 0;
        for (int b = 0; b < NB; ++b) { base[b] = run; run += tot[b]; }
    }
    __syncthreads();
    if (t < NB) {
        int run = base[t];
        bucketBase[t] = run;
        for (int k = 0; k < NBLK; ++k) {
            blkOfs[k * NB + t] = run;
            run += hist_blk[k * NB + t];
        }
    }
}

// ---------------- phase 2: bin edges into bucket-grouped array (no atomics) ----------
__global__ __launch_bounds__(256) void bin_edges(const int* __restrict__ eidx,
                                                 const int* __restrict__ blkOfs,
                                                 unsigned* __restrict__ binned) {
    __shared__ unsigned staged[CHUNK];
    __shared__ int lhist[NB];
    __shared__ int lscan[NB];
    __shared__ int cnt2[NB];
    __shared__ int gofs[NB];
    int tid = threadIdx.x;
    for (int t = tid; t < NB; t += 256) { lhist[t] = 0; cnt2[t] = 0; }
    __syncthreads();
    int base = blockIdx.x * CHUNK;
    unsigned pk[CHUNK / 256];
#pragma unroll
    for (int j = 0; j < CHUNK / 256; ++j) {
        int i = base + j * 256 + tid;
        pk[j] = 0xFFFFFFFFu;
        if (i < EPE) {
            int s, d;
            if (i < EE) { s = eidx[i]; d = eidx[EE + i]; } else { s = i - EE; d = i - EE; }
            pk[j] = ((unsigned)s << 16) | (unsigned)d;
            atomicAdd(&lhist[d >> 9], 1);
        }
    }
    __syncthreads();
    if (tid == 0) {
        int run = 0;
        for (int b = 0; b < NB; ++b) { lscan[b] = run; run += lhist[b]; }
    }
    __syncthreads();
#pragma unroll
    for (int j = 0; j < CHUNK / 256; ++j) {
        if (pk[j] != 0xFFFFFFFFu) {
            int b = (int)((pk[j] & 0xFFFFu) >> 9);
            int lp = lscan[b] + atomicAdd(&cnt2[b], 1);
            staged[lp] = pk[j];
        }
    }
    for (int t = tid; t < NB; t += 256) gofs[t] = blkOfs[blockIdx.x * NB + t];
    __syncthreads();
    int nTot = lscan[NB - 1] + lhist[NB - 1];
    for (int i = tid; i < nTot; i += 256) {
        unsigned p = staged[i];
        int b = (int)((p & 0xFFFFu) >> 9);
        binned[gofs[b] + (i - lscan[b])] = p;
    }
}

// ---------------- phase 3: per-bucket in-LDS sort -> contiguous csr write ------------
__global__ __launch_bounds__(256) void build_csr(const unsigned* __restrict__ binned,
                                                 const int* __restrict__ offs,
                                                 int* __restrict__ csr) {
    __shared__ int lcsr[BCAP];
    __shared__ int lcnt[512];
    int b = blockIdx.x, tid = threadIdx.x;
    int n0 = b * 512;
    int nEnd = min(n0 + 512, NN);
    int o0 = offs[n0];
    for (int j = tid; j < 512; j += 256) {
        int node = n0 + j;
        lcnt[j] = (node < nEnd) ? (offs[node] - o0) : 0;
    }
    __syncthreads();
    int nTot = offs[nEnd] - o0;
    if (nTot > BCAP) nTot = BCAP;   // safety (never triggers for this data)
    for (int i = tid; i < nTot; i += 256) {
        unsigned p = binned[o0 + i];
        int dl = (int)(p & 511u);
        int src = (int)(p >> 16);
        int pos = atomicAdd(&lcnt[dl], 1);
        if (pos < BCAP) lcsr[pos] = src;
    }
    __syncthreads();
    for (int i = tid; i < nTot; i += 256)
        csr[o0 + i] = lcsr[i];
}

// ---------------- encoder GEMM: h(f32) = silu(LN(x@W0 + b0)) ----------------
__global__ __launch_bounds__(256) void gemm_encoder(
    const float* __restrict__ x, const unsigned short* __restrict__ WT,
    const float* __restrict__ b0, const float* __restrict__ g0,
    const float* __restrict__ be0, float* __restrict__ h) {
    int wave = threadIdx.x >> 6, lane = threadIdx.x & 63;
    int cl = lane & 15, q = lane >> 4;
    int row0 = blockIdx.x * 64 + wave * 16;
    int rA = row0 + cl; if (rA >= NN) rA = NN - 1;
    int kq = q * 8;
    f32x4 acc[8];
#pragma unroll
    for (int t = 0; t < 8; ++t) acc[t] = (f32x4){0.f, 0.f, 0.f, 0.f};
#pragma unroll
    for (int k0 = 0; k0 < 128; k0 += 32) {
        const float* xr = x + rA * 128 + k0 + kq;
        f32x4 f0 = *(const f32x4*)(xr);
        f32x4 f1 = *(const f32x4*)(xr + 4);
        bf16x8 a;
#pragma unroll
        for (int j = 0; j < 4; ++j) {
            a[j] = (short)f2bf(f0[j]);
            a[4 + j] = (short)f2bf(f1[j]);
        }
#pragma unroll
        for (int t = 0; t < 8; ++t) {
            bf16x8 b = *(const bf16x8*)(WT + (t * 16 + cl) * 128 + k0 + kq);
            acc[t] = __builtin_amdgcn_mfma_f32_16x16x32_bf16(a, b, acc[t], 0, 0, 0);
        }
    }
    float bcol[8], gcol[8], becol[8];
#pragma unroll
    for (int t = 0; t < 8; ++t) {
        int c = t * 16 + cl;
        bcol[t] = b0[c]; gcol[t] = g0[c]; becol[t] = be0[c];
    }
#pragma unroll
    for (int r = 0; r < 4; ++r) {
        int row = row0 + q * 4 + r;
        float v[8], s = 0.f, ss = 0.f;
#pragma unroll
        for (int t = 0; t < 8; ++t) {
            v[t] = acc[t][r] + bcol[t];
            s += v[t]; ss += v[t] * v[t];
        }
#pragma unroll
        for (int m = 1; m <= 8; m <<= 1) {
            s += __shfl_xor(s, m, 64); ss += __shfl_xor(ss, m, 64);
        }
        float mu = s * (1.f / 128.f);
        float var = ss * (1.f / 128.f) - mu * mu;
        float rstd = rsqrtf(var + 1e-5f);
        if (row < NN) {
#pragma unroll
            for (int t = 0; t < 8; ++t) {
                float y = (v[t] - mu) * rstd * gcol[t] + becol[t];
                h[row * 128 + t * 16 + cl] = silu(y);
            }
        }
    }
}

// ---------------- GAT GEMM: hh = h@Wg[l] (bf16), a_s/a_d/es per node ----------------
__global__ __launch_bounds__(256) void gemm_gat(
    const float* __restrict__ h, const unsigned short* __restrict__ WT,
    const float* __restrict__ atts, const float* __restrict__ attd,
    unsigned short* __restrict__ hh, float* __restrict__ a_s, float* __restrict__ a_d,
    float* __restrict__ es) {
    int wave = threadIdx.x >> 6, lane = threadIdx.x & 63;
    int cl = lane & 15, q = lane >> 4;
    int row0 = blockIdx.x * 64 + wave * 16;
    int rA = row0 + cl; if (rA >= NN) rA = NN - 1;
    int kq = q * 8;
    f32x4 acc[8];
#pragma unroll
    for (int t = 0; t < 8; ++t) acc[t] = (f32x4){0.f, 0.f, 0.f, 0.f};
#pragma unroll
    for (int k0 = 0; k0 < 128; k0 += 32) {
        const float* hrow = h + rA * 128;
        f32x4 f0 = *(const f32x4*)(hrow + k0 + kq);
        f32x4 f1 = *(const f32x4*)(hrow + k0 + kq + 4);
        bf16x8 a;
#pragma unroll
        for (int j = 0; j < 4; ++j) {
            a[j] = (short)f2bf(f0[j]);
            a[4 + j] = (short)f2bf(f1[j]);
        }
#pragma unroll
        for (int t = 0; t < 8; ++t) {
            bf16x8 b = *(const bf16x8*)(WT + (t * 16 + cl) * 128 + k0 + kq);
            acc[t] = __builtin_amdgcn_mfma_f32_16x16x32_bf16(a, b, acc[t], 0, 0, 0);
        }
    }
#pragma unroll
    for (int r = 0; r < 4; ++r) {
        int row = row0 + q * 4 + r;
        if (row < NN) {
#pragma unroll
            for (int t = 0; t < 8; ++t)
                hh[row * 128 + t * 16 + cl] = f2bf(acc[t][r]);
        }
    }
    float as_lo[4], as_hi[4], ad_lo[4], ad_hi[4];
#pragma unroll
    for (int hd = 0; hd < 4; ++hd) {
        as_lo[hd] = atts[hd * 32 + cl];      as_hi[hd] = atts[hd * 32 + 16 + cl];
        ad_lo[hd] = attd[hd * 32 + cl];      ad_hi[hd] = attd[hd * 32 + 16 + cl];
    }
#pragma unroll
    for (int r = 0; r < 4; ++r) {
        int row = row0 + q * 4 + r;
        float ps[4], pd[4];
#pragma unroll
        for (int hd = 0; hd < 4; ++hd) {
            float v0 = acc[2 * hd][r], v1 = acc[2 * hd + 1][r];
            ps[hd] = v0 * as_lo[hd] + v1 * as_hi[hd];
            pd[hd] = v0 * ad_lo[hd] + v1 * ad_hi[hd];
        }
#pragma unroll
        for (int m = 1; m <= 8; m <<= 1) {
#pragma unroll
            for (int hd = 0; hd < 4; ++hd) {
                ps[hd] += __shfl_xor(ps[hd], m, 64);
                pd[hd] += __shfl_xor(pd[hd], m, 64);
            }
        }
        if (row < NN && cl < 4) {
            float vs = (cl == 0) ? ps[0] : (cl == 1) ? ps[1] : (cl == 2) ? ps[2] : ps[3];
            float vd = (cl == 0) ? pd[0] : (cl == 1) ? pd[1] : (cl == 2) ? pd[2] : pd[3];
            a_s[row * 4 + cl] = vs;
            a_d[row * 4 + cl] = vd;
            float e = vs + vd;                       // self-loop logit
            es[row * 4 + cl] = (e > 0.f) ? e : 0.2f * e;
        }
    }
}

// ---------------- fused aggregation (R5-proven shape): LDS weights + 4-chain ILP ------
__global__ __launch_bounds__(256) void gat_aggregate(
    const int* __restrict__ offs, const int* __restrict__ csr,
    const float* __restrict__ a_s, const float* __restrict__ a_d,
    const float* __restrict__ es, const unsigned short* __restrict__ hh,
    float* __restrict__ h,
    const float* __restrict__ bg, const float* __restrict__ gg,
    const float* __restrict__ bgg) {
    __shared__ f32x4 lw[4][MAXCH];
    int wv = threadIdx.x >> 6;
    int node = blockIdx.x * 4 + wv;
    int lane = threadIdx.x & 63;
    if (node >= NN) return;
    int e0 = offs[node], e1 = offs[node + 1];
    int c0 = lane * 2, hd = lane >> 4;
    f32x4 ad4 = *(const f32x4*)(a_d + node * 4);
    f32x4 e4  = *(const f32x4*)(es  + node * 4);
    float d0 = 0.f, d1 = 0.f, d2 = 0.f, d3 = 0.f;
    float x0 = 0.f, y0 = 0.f, x1 = 0.f, y1 = 0.f;
    float x2 = 0.f, y2 = 0.f, x3 = 0.f, y3 = 0.f;
    for (int base = e0; base < e1; base += MAXCH) {
        int cend = min(e1, base + MAXCH);
        for (int e = base + lane; e < cend; e += 64) {
            int s = csr[e];
            f32x4 as = *(const f32x4*)(a_s + s * 4);
            f32x4 o;
#pragma unroll
            for (int k = 0; k < 4; ++k) {
                float qq = as[k] + ad4[k];
                qq = (qq > 0.f) ? qq : 0.2f * qq;
                o[k] = __expf(qq - e4[k]);
            }
            lw[wv][e - base] = o;
        }
        asm volatile("s_waitcnt lgkmcnt(0)" ::: "memory");
        int e = base;
        for (; e + 4 <= cend; e += 4) {
            int s0 = csr[e], s1 = csr[e + 1], s2 = csr[e + 2], s3 = csr[e + 3];
            float w0 = lw[wv][e - base + 0][hd];
            float w1 = lw[wv][e - base + 1][hd];
            float w2 = lw[wv][e - base + 2][hd];
            float w3 = lw[wv][e - base + 3][hd];
            unsigned v0 = *(const unsigned*)(hh + s0 * 128 + c0);
            unsigned v1 = *(const unsigned*)(hh + s1 * 128 + c0);
            unsigned v2 = *(const unsigned*)(hh + s2 * 128 + c0);
            unsigned v3 = *(const unsigned*)(hh + s3 * 128 + c0);
            d0 += w0; x0 += w0 * bf2f((unsigned short)(v0 & 0xFFFFu)); y0 += w0 * bf2f((unsigned short)(v0 >> 16));
            d1 += w1; x1 += w1 * bf2f((unsigned short)(v1 & 0xFFFFu)); y1 += w1 * bf2f((unsigned short)(v1 >> 16));
            d2 += w2; x2 += w2 * bf2f((unsigned short)(v2 & 0xFFFFu)); y2 += w2 * bf2f((unsigned short)(v2 >> 16));
            d3 += w3; x3 += w3 * bf2f((unsigned short)(v3 & 0xFFFFu)); y3 += w3 * bf2f((unsigned short)(v3 >> 16));
        }
        for (; e < cend; ++e) {
            int s0 = csr[e];
            float w0 = lw[wv][e - base][hd];
            unsigned v0 = *(const unsigned*)(hh + s0 * 128 + c0);
            d0 += w0; x0 += w0 * bf2f((unsigned short)(v0 & 0xFFFFu)); y0 += w0 * bf2f((unsigned short)(v0 >> 16));
        }
        if (cend < e1)
            asm volatile("s_waitcnt lgkmcnt(0)" ::: "memory");
    }
    float den = (d0 + d1) + (d2 + d3);
    float X = (x0 + x1) + (x2 + x3);
    float Y = (y0 + y1) + (y2 + y3);
    float inv = 1.f / den;
    float o0 = X * inv + bg[c0];
    float o1 = Y * inv + bg[c0 + 1];
    float s = o0 + o1, ss = o0 * o0 + o1 * o1;
#pragma unroll
    for (int m = 1; m <= 32; m <<= 1) {
        s += __shfl_xor(s, m, 64); ss += __shfl_xor(ss, m, 64);
    }
    float mu = s * (1.f / 128.f);
    float var = ss * (1.f / 128.f) - mu * mu;
    float rstd = rsqrtf(var + 1e-5f);
    float yy0 = (o0 - mu) * rstd * gg[c0] + bgg[c0];
    float yy1 = (o1 - mu) * rstd * gg[c0 + 1] + bgg[c0 + 1];
    float id0 = h[node * 128 + c0], id1 = h[node * 128 + c0 + 1];
    h[node * 128 + c0]     = silu(yy0) + id0;
    h[node * 128 + c0 + 1] = silu(yy1) + id1;
}

// ---------------- mean pool per graph (batch sorted); counts from hist ----------------
__global__ void pool_kernel(const float* __restrict__ h, const int* __restrict__ batch,
                            float* __restrict__ pooled) {
    int c = threadIdx.x;
    int r0 = blockIdx.x * 64;
    int rend = r0 + 64; if (rend > NN) rend = NN;
    int cur = batch[r0];
    float acc = 0.f;
    for (int r = r0; r < rend; ++r) {
        int b = batch[r];
        float v = h[r * 128 + c];
        if (b != cur) {
            atomicAdd(&pooled[cur * 128 + c], acc);
            acc = 0.f; cur = b;
        }
        acc += v;
    }
    atomicAdd(&pooled[cur * 128 + c], acc);
}

// ---------------- head: silu(LN(pooled/cnt @ Wp + bp)) -> f32 out ----------------
__global__ void final_kernel(const float* __restrict__ pooled, const float* __restrict__ cntArr,
                             const float* __restrict__ Wp, const float* __restrict__ bp,
                             const float* __restrict__ gp, const float* __restrict__ bep,
                             float* __restrict__ out) {
    __shared__ float p[128];
    __shared__ float red[128];
    int g = blockIdx.x, c = threadIdx.x;
    float cnt = cntArr[g]; if (cnt < 1.f) cnt = 1.f;
    p[c] = pooled[g * 128 + c] / cnt;
    __syncthreads();
    float acc = bp[c];
    for (int k = 0; k < 128; ++k) acc += p[k] * Wp[k * 128 + c];
    red[c] = acc;
    __syncthreads();
    if (c < 64) {
        float s = red[c] + red[c + 64];
#pragma unroll
        for (int m = 1; m <= 32; m <<= 1) s += __shfl_xor(s, m, 64);
        if (c == 0) red[0] = s;
    }
    __syncthreads();
    float mu = red[0] * (1.f / 128.f);
    __syncthreads();
    float dv = acc - mu;
    red[c] = dv * dv;
    __syncthreads();
    if (c < 64) {
        float s = red[c] + red[c + 64];
#pragma unroll
        for (int m = 1; m <= 32; m <<= 1) s += __shfl_xor(s, m, 64);
        if (c == 0) red[0] = s;
    }
    __syncthreads();
    float var = red[0] * (1.f / 128.f);
    float rstd = rsqrtf(var + 1e-5f);
    float y = dv * rstd * gp[c] + bep[c];
    out[g * 128 + c] = silu(y);
}

extern "C" void kernel_launch(void* const* d_in, const int* in_sizes, int n_in,
                              void* d_out, int out_size, void* d_ws, size_t ws_size,
                              hipStream_t stream) {
    const float* x    = (const float*)d_in[0];
    const int*   eidx = (const int*)d_in[1];
    const int*   batch= (const int*)d_in[2];
    const float* W0   = (const float*)d_in[3];
    const float* b0   = (const float*)d_in[4];
    const float* g0   = (const float*)d_in[5];
    const float* be0  = (const float*)d_in[6];
    const float* Wg   = (const float*)d_in[7];
    const float* atts = (const float*)d_in[8];
    const float* attd = (const float*)d_in[9];
    const float* bg   = (const float*)d_in[10];
    const float* gg   = (const float*)d_in[11];
    const float* bgg  = (const float*)d_in[12];
    const float* Wp   = (const float*)d_in[13];
    const float* bp   = (const float*)d_in[14];
    const float* gp   = (const float*)d_in[15];
    const float* bep  = (const float*)d_in[16];

    char* ws = (char*)d_ws;
    size_t off = 0;
    auto alloc = [&](size_t bytes) {
        void* p = ws + off;
        off = (off + bytes + 255) & ~(size_t)255;
        return p;
    };
    float*          h        = (float*)alloc((size_t)NPAD * 128 * 4);
    unsigned short* hh       = (unsigned short*)alloc((size_t)NN * 128 * 2);
    float*          a_s      = (float*)alloc((size_t)NN * 4 * 4);
    float*          a_d      = (float*)alloc((size_t)NN * 4 * 4);
    float*          es       = (float*)alloc((size_t)NN * 4 * 4);
    int*            offs     = (int*)alloc((size_t)(NN + 1) * 4);
    int*            counts   = (int*)alloc((size_t)NN * 4);
    int*            csr      = (int*)alloc((size_t)EPE * 4);
    unsigned*       binned   = (unsigned*)alloc((size_t)EPE * 4);
    int*            hist_blk = (int*)alloc((size_t)NBLK * NB * 4);
    int*            blkOfs   = (int*)alloc((size_t)NBLK * NB * 4);
    int*            bktBase  = (int*)alloc((size_t)NB * 4);
    int*            parts    = (int*)alloc(256 * 4);
    unsigned short* WT       = (unsigned short*)alloc(4 * 16384 * 2);
    float*          pooled   = (float*)alloc((size_t)(BGR * 128 + BGR) * 4);
    float*          cntArr   = pooled + BGR * 128;

    hipMemsetAsync(counts, 0, (size_t)NN * 4, stream);
    hipMemsetAsync(pooled, 0, (size_t)(BGR * 128 + BGR) * 4, stream);

    transpose_w<<<4, 256, 0, stream>>>(W0, Wg, WT);
    count_edges<<<(EPE + 255) / 256, 256, 0, stream>>>(eidx, counts, batch, cntArr);
    bucket_hist<<<NBLK, 256, 0, stream>>>(eidx, hist_blk);
    int nb = (NN + 255) / 256;
    scan1<<<nb, 256, 0, stream>>>(counts, offs, parts);
    scan2<<<1, 256, 0, stream>>>(parts, nb);
    scan3<<<nb, 256, 0, stream>>>(offs, parts);
    scan_buckets<<<1, 128, 0, stream>>>(hist_blk, blkOfs, bktBase);
    bin_edges<<<NBLK, 256, 0, stream>>>(eidx, blkOfs, binned);
    build_csr<<<NB, 256, 0, stream>>>(binned, offs, csr);

    gemm_encoder<<<NPAD / 64, 256, 0, stream>>>(x, WT, b0, g0, be0, h);
    for (int l = 0; l < 3; ++l) {
        gemm_gat<<<NPAD / 64, 256, 0, stream>>>(h, WT + (l + 1) * 16384,
                                                atts + l * 128, attd + l * 128,
                                                hh, a_s, a_d, es);
        gat_aggregate<<<(NN + 3) / 4, 256, 0, stream>>>(offs, csr, a_s, a_d, es, hh, h,
                                                        bg + l * 128, gg + l * 128,
                                                        bgg + l * 128);
    }
    pool_kernel<<<(NN + 63) / 64, 128, 0, stream>>>(h, batch, pooled);
    final_kernel<<<BGR, 128, 0, stream>>>(pooled, cntArr, Wp, bp, gp, bep, (float*)d_out);
}

// Round 11
// 443.154 us; speedup vs baseline: 1.5951x; 1.0475x over previous
//
#include <hip/hip_runtime.h>

#define NN    50000
#define EE    800000
#define EPE   850000     // EE + NN self loops
#define NPAD  50048      // multiple of 64
#define BGR   64
#define MAXCH 128        // edge chunk per node held in LDS (aggregate)
#define NB    98         // buckets of 512 nodes
#define CHUNK 4096       // edges per binning block
#define NBLK  208        // ceil(EPE / CHUNK)
#define BCAP  12288      // per-bucket LDS capacity in build_csr

typedef __attribute__((ext_vector_type(8))) short bf16x8;
typedef __attribute__((ext_vector_type(4))) float f32x4;

__device__ __forceinline__ float bf2f(unsigned short u) {
    return __uint_as_float(((unsigned)u) << 16);
}
__device__ __forceinline__ unsigned short f2bf(float f) {
    unsigned u = __float_as_uint(f);
    unsigned r = (u + 0x7FFFu + ((u >> 16) & 1u)) >> 16;
    return (unsigned short)r;
}
__device__ __forceinline__ float silu(float y) { return y / (1.f + __expf(-y)); }

// ---------------- weight transpose: WT[m][col][k] = f2bf(W[m][k][col]) ----------------
__global__ void transpose_w(const float* __restrict__ W0, const float* __restrict__ Wg,
                            unsigned short* __restrict__ WT) {
    __shared__ unsigned short tile[128][129];
    int m = blockIdx.x;
    const float* src = (m == 0) ? W0 : (Wg + (m - 1) * 16384);
    unsigned short* dst = WT + m * 16384;
    for (int i = threadIdx.x; i < 16384; i += 256) tile[i >> 7][i & 127] = f2bf(src[i]);
    __syncthreads();
    for (int i = threadIdx.x; i < 16384; i += 256) {
        int c = i >> 7, k = i & 127;
        dst[i] = tile[k][c];
    }
}

// ---------------- count in-degree + per-graph node histogram ----------------
__global__ void count_edges(const int* __restrict__ eidx, int* __restrict__ counts,
                            const int* __restrict__ batch, float* __restrict__ cntArr) {
    __shared__ float lh[BGR];
    bool doHist = (blockIdx.x < 196);
    int i = blockIdx.x * 256 + threadIdx.x;
    if (doHist) {
        if (threadIdx.x < BGR) lh[threadIdx.x] = 0.f;
        __syncthreads();
    }
    if (i < EPE) {
        int d = (i < EE) ? eidx[EE + i] : (i - EE);
        atomicAdd(&counts[d], 1);
    }
    if (doHist) {
        if (i < NN) atomicAdd(&lh[batch[i]], 1.f);
        __syncthreads();
        if (threadIdx.x < BGR) {
            float v = lh[threadIdx.x];
            if (v != 0.f) atomicAdd(&cntArr[threadIdx.x], v);
        }
    }
}

// ---------------- 3-kernel exclusive scan over per-node counts ----------------
__global__ void scan1(const int* __restrict__ counts, int* __restrict__ offs,
                      int* __restrict__ partials) {
    __shared__ int sm[256];
    int t = threadIdx.x, i = blockIdx.x * 256 + t;
    int x = (i < NN) ? counts[i] : 0;
    sm[t] = x; __syncthreads();
    for (int d = 1; d < 256; d <<= 1) {
        int v = (t >= d) ? sm[t - d] : 0;
        __syncthreads(); sm[t] += v; __syncthreads();
    }
    if (i < NN) offs[i] = sm[t] - x;
    if (t == 255) partials[blockIdx.x] = sm[255];
}

__global__ void scan2(int* __restrict__ partials, int nb) {
    __shared__ int sm[256];
    int t = threadIdx.x;
    int x = (t < nb) ? partials[t] : 0;
    sm[t] = x; __syncthreads();
    for (int d = 1; d < 256; d <<= 1) {
        int v = (t >= d) ? sm[t - d] : 0;
        __syncthreads(); sm[t] += v; __syncthreads();
    }
    if (t < nb) partials[t] = sm[t] - x;
}

__global__ void scan3(int* __restrict__ offs, const int* __restrict__ partials) {
    int i = blockIdx.x * 256 + threadIdx.x;
    if (i < NN) offs[i] += partials[blockIdx.x];
    if (i == 0) offs[NN] = EPE;
}

// ---------------- bucketed CSR build, phase 0: per-block bucket histograms ----------
__global__ __launch_bounds__(256) void bucket_hist(const int* __restrict__ eidx,
                                                   int* __restrict__ hist_blk) {
    __shared__ int lh[NB];
    for (int t = threadIdx.x; t < NB; t += 256) lh[t] = 0;
    __syncthreads();
    int base = blockIdx.x * CHUNK;
#pragma unroll
    for (int j = 0; j < CHUNK / 256; ++j) {
        int i = base + j * 256 + threadIdx.x;
        if (i < EPE) {
            int d = (i < EE) ? eidx[EE + i] : (i - EE);
            atomicAdd(&lh[d >> 9], 1);
        }
    }
    __syncthreads();
    for (int t = threadIdx.x; t < NB; t += 256)
        hist_blk[blockIdx.x * NB + t] = lh[t];
}

// ---------------- phase 1: 2D exclusive scan -> per-block per-bucket offsets ----------
__global__ void scan_buckets(const int* __restrict__ hist_blk, int* __restrict__ blkOfs,
                             int* __restrict__ bucketBase) {
    __shared__ int tot[NB];
    __shared__ int base[NB];
    int t = threadIdx.x;
    if (t < NB) {
        int s = 0;
        for (int k = 0; k < NBLK; ++k) s += hist_blk[k * NB + t];
        tot[t] = s;
    }
    __syncthreads();
    if (t == 0) {
        int run = 0;
        for (int b = 0; b < NB; ++b) { base[b] = run; run += tot[b]; }
    }
    __syncthreads();
    if (t < NB) {
        int run = base[t];
        bucketBase[t] = run;
        for (int k = 0; k < NBLK; ++k) {
            blkOfs[k * NB + t] = run;
            run += hist_blk[k * NB + t];
        }
    }
}

// ---------------- phase 2: bin edges into bucket-grouped array (no global atomics) ----
__global__ __launch_bounds__(256) void bin_edges(const int* __restrict__ eidx,
                                                 const int* __restrict__ blkOfs,
                                                 unsigned* __restrict__ binned) {
    __shared__ unsigned staged[CHUNK];
    __shared__ int lhist[NB];
    __shared__ int lscan[NB];
    __shared__ int cnt2[NB];
    __shared__ int gofs[NB];
    int tid = threadIdx.x;
    for (int t = tid; t < NB; t += 256) { lhist[t] = 0; cnt2[t] = 0; }
    __syncthreads();
    int base = blockIdx.x * CHUNK;
    unsigned pk[CHUNK / 256];
#pragma unroll
    for (int j = 0; j < CHUNK / 256; ++j) {
        int i = base + j * 256 + tid;
        pk[j] = 0xFFFFFFFFu;
        if (i < EPE) {
            int s, d;
            if (i < EE) { s = eidx[i]; d = eidx[EE + i]; } else { s = i - EE; d = i - EE; }
            pk[j] = ((unsigned)s << 16) | (unsigned)d;
            atomicAdd(&lhist[d >> 9], 1);
        }
    }
    __syncthreads();
    if (tid == 0) {
        int run = 0;
        for (int b = 0; b < NB; ++b) { lscan[b] = run; run += lhist[b]; }
    }
    __syncthreads();
#pragma unroll
    for (int j = 0; j < CHUNK / 256; ++j) {
        if (pk[j] != 0xFFFFFFFFu) {
            int b = (int)((pk[j] & 0xFFFFu) >> 9);
            int lp = lscan[b] + atomicAdd(&cnt2[b], 1);
            staged[lp] = pk[j];
        }
    }
    for (int t = tid; t < NB; t += 256) gofs[t] = blkOfs[blockIdx.x * NB + t];
    __syncthreads();
    int nTot = lscan[NB - 1] + lhist[NB - 1];
    for (int i = tid; i < nTot; i += 256) {
        unsigned p = staged[i];
        int b = (int)((p & 0xFFFFu) >> 9);
        binned[gofs[b] + (i - lscan[b])] = p;
    }
}

// ---------------- phase 3: per-bucket in-LDS sort -> contiguous csr write ------------
__global__ __launch_bounds__(256) void build_csr(const unsigned* __restrict__ binned,
                                                 const int* __restrict__ offs,
                                                 int* __restrict__ csr) {
    __shared__ int lcsr[BCAP];
    __shared__ int lcnt[512];
    int b = blockIdx.x, tid = threadIdx.x;
    int n0 = b * 512;
    int nEnd = min(n0 + 512, NN);
    int o0 = offs[n0];
    for (int j = tid; j < 512; j += 256) {
        int node = n0 + j;
        lcnt[j] = (node < nEnd) ? (offs[node] - o0) : 0;
    }
    __syncthreads();
    int nTot = offs[nEnd] - o0;
    if (nTot > BCAP) nTot = BCAP;
    for (int i = tid; i < nTot; i += 256) {
        unsigned p = binned[o0 + i];
        int dl = (int)(p & 511u);
        int src = (int)(p >> 16);
        int pos = atomicAdd(&lcnt[dl], 1);
        if (pos < BCAP) lcsr[pos] = src;
    }
    __syncthreads();
    for (int i = tid; i < nTot; i += 256)
        csr[o0 + i] = lcsr[i];
}

// ---------------- encoder GEMM: h(f32) = silu(LN(x@W0 + b0)) ----------------
__global__ __launch_bounds__(256) void gemm_encoder(
    const float* __restrict__ x, const unsigned short* __restrict__ WT,
    const float* __restrict__ b0, const float* __restrict__ g0,
    const float* __restrict__ be0, float* __restrict__ h) {
    int wave = threadIdx.x >> 6, lane = threadIdx.x & 63;
    int cl = lane & 15, q = lane >> 4;
    int row0 = blockIdx.x * 64 + wave * 16;
    int rA = row0 + cl; if (rA >= NN) rA = NN - 1;
    int kq = q * 8;
    f32x4 acc[8];
#pragma unroll
    for (int t = 0; t < 8; ++t) acc[t] = (f32x4){0.f, 0.f, 0.f, 0.f};
#pragma unroll
    for (int k0 = 0; k0 < 128; k0 += 32) {
        const float* xr = x + rA * 128 + k0 + kq;
        f32x4 f0 = *(const f32x4*)(xr);
        f32x4 f1 = *(const f32x4*)(xr + 4);
        bf16x8 a;
#pragma unroll
        for (int j = 0; j < 4; ++j) {
            a[j] = (short)f2bf(f0[j]);
            a[4 + j] = (short)f2bf(f1[j]);
        }
#pragma unroll
        for (int t = 0; t < 8; ++t) {
            bf16x8 b = *(const bf16x8*)(WT + (t * 16 + cl) * 128 + k0 + kq);
            acc[t] = __builtin_amdgcn_mfma_f32_16x16x32_bf16(a, b, acc[t], 0, 0, 0);
        }
    }
    float bcol[8], gcol[8], becol[8];
#pragma unroll
    for (int t = 0; t < 8; ++t) {
        int c = t * 16 + cl;
        bcol[t] = b0[c]; gcol[t] = g0[c]; becol[t] = be0[c];
    }
#pragma unroll
    for (int r = 0; r < 4; ++r) {
        int row = row0 + q * 4 + r;
        float v[8], s = 0.f, ss = 0.f;
#pragma unroll
        for (int t = 0; t < 8; ++t) {
            v[t] = acc[t][r] + bcol[t];
            s += v[t]; ss += v[t] * v[t];
        }
#pragma unroll
        for (int m = 1; m <= 8; m <<= 1) {
            s += __shfl_xor(s, m, 64); ss += __shfl_xor(ss, m, 64);
        }
        float mu = s * (1.f / 128.f);
        float var = ss * (1.f / 128.f) - mu * mu;
        float rstd = rsqrtf(var + 1e-5f);
        if (row < NN) {
#pragma unroll
            for (int t = 0; t < 8; ++t) {
                float y = (v[t] - mu) * rstd * gcol[t] + becol[t];
                h[row * 128 + t * 16 + cl] = silu(y);
            }
        }
    }
}

// ---------------- GAT GEMM: hh = h@Wg[l] (bf16), a_s/a_d/es per node ----------------
__global__ __launch_bounds__(256) void gemm_gat(
    const float* __restrict__ h, const unsigned short* __restrict__ WT,
    const float* __restrict__ atts, const float* __restrict__ attd,
    unsigned short* __restrict__ hh, float* __restrict__ a_s, float* __restrict__ a_d,
    float* __restrict__ es) {
    int wave = threadIdx.x >> 6, lane = threadIdx.x & 63;
    int cl = lane & 15, q = lane >> 4;
    int row0 = blockIdx.x * 64 + wave * 16;
    int rA = row0 + cl; if (rA >= NN) rA = NN - 1;
    int kq = q * 8;
    f32x4 acc[8];
#pragma unroll
    for (int t = 0; t < 8; ++t) acc[t] = (f32x4){0.f, 0.f, 0.f, 0.f};
#pragma unroll
    for (int k0 = 0; k0 < 128; k0 += 32) {
        const float* hrow = h + rA * 128;
        f32x4 f0 = *(const f32x4*)(hrow + k0 + kq);
        f32x4 f1 = *(const f32x4*)(hrow + k0 + kq + 4);
        bf16x8 a;
#pragma unroll
        for (int j = 0; j < 4; ++j) {
            a[j] = (short)f2bf(f0[j]);
            a[4 + j] = (short)f2bf(f1[j]);
        }
#pragma unroll
        for (int t = 0; t < 8; ++t) {
            bf16x8 b = *(const bf16x8*)(WT + (t * 16 + cl) * 128 + k0 + kq);
            acc[t] = __builtin_amdgcn_mfma_f32_16x16x32_bf16(a, b, acc[t], 0, 0, 0);
        }
    }
#pragma unroll
    for (int r = 0; r < 4; ++r) {
        int row = row0 + q * 4 + r;
        if (row < NN) {
#pragma unroll
            for (int t = 0; t < 8; ++t)
                hh[row * 128 + t * 16 + cl] = f2bf(acc[t][r]);
        }
    }
    float as_lo[4], as_hi[4], ad_lo[4], ad_hi[4];
#pragma unroll
    for (int hd = 0; hd < 4; ++hd) {
        as_lo[hd] = atts[hd * 32 + cl];      as_hi[hd] = atts[hd * 32 + 16 + cl];
        ad_lo[hd] = attd[hd * 32 + cl];      ad_hi[hd] = attd[hd * 32 + 16 + cl];
    }
#pragma unroll
    for (int r = 0; r < 4; ++r) {
        int row = row0 + q * 4 + r;
        float ps[4], pd[4];
#pragma unroll
        for (int hd = 0; hd < 4; ++hd) {
            float v0 = acc[2 * hd][r], v1 = acc[2 * hd + 1][r];
            ps[hd] = v0 * as_lo[hd] + v1 * as_hi[hd];
            pd[hd] = v0 * ad_lo[hd] + v1 * ad_hi[hd];
        }
#pragma unroll
        for (int m = 1; m <= 8; m <<= 1) {
#pragma unroll
            for (int hd = 0; hd < 4; ++hd) {
                ps[hd] += __shfl_xor(ps[hd], m, 64);
                pd[hd] += __shfl_xor(pd[hd], m, 64);
            }
        }
        if (row < NN && cl < 4) {
            float vs = (cl == 0) ? ps[0] : (cl == 1) ? ps[1] : (cl == 2) ? ps[2] : ps[3];
            float vd = (cl == 0) ? pd[0] : (cl == 1) ? pd[1] : (cl == 2) ? pd[2] : pd[3];
            a_s[row * 4 + cl] = vs;
            a_d[row * 4 + cl] = vd;
            float e = vs + vd;                       // self-loop logit
            es[row * 4 + cl] = (e > 0.f) ? e : 0.2f * e;
        }
    }
}

// ---------------- aggregation: 2 nodes per wave (8/block), 4 cols/lane, LDS weights ---
__global__ __launch_bounds__(256) void gat_aggregate(
    const int* __restrict__ offs, const int* __restrict__ csr,
    const float* __restrict__ a_s, const float* __restrict__ a_d,
    const float* __restrict__ es, const unsigned short* __restrict__ hh,
    float* __restrict__ h,
    const float* __restrict__ bg, const float* __restrict__ gg,
    const float* __restrict__ bgg) {
    __shared__ f32x4 lw[8][MAXCH];
    int wv = threadIdx.x >> 6;
    int lane = threadIdx.x & 63;
    int half = lane >> 5;               // which node of the wave
    int l32 = lane & 31;
    int ns = wv * 2 + half;             // node slot in block (0..7)
    int node = blockIdx.x * 8 + ns;     // NN % 8 == 0: always valid
    int e0 = offs[node], e1 = offs[node + 1];
    int c0 = l32 * 4;                   // 4 columns per lane
    int hd = l32 >> 3;                  // head of this lane's columns
    f32x4 ad4 = *(const f32x4*)(a_d + node * 4);
    f32x4 e4  = *(const f32x4*)(es  + node * 4);
    float dacc[4];
    f32x4 xacc[4];
#pragma unroll
    for (int u = 0; u < 4; ++u) {
        dacc[u] = 0.f;
        xacc[u] = (f32x4){0.f, 0.f, 0.f, 0.f};
    }
    for (int base = e0; base < e1; base += MAXCH) {
        int cend = min(e1, base + MAXCH);
        // phase A: 32 lanes of this node compute softmax weights (all 4 heads)
        for (int e = base + l32; e < cend; e += 32) {
            int s = csr[e];
            f32x4 as = *(const f32x4*)(a_s + s * 4);
            f32x4 o;
#pragma unroll
            for (int k = 0; k < 4; ++k) {
                float qq = as[k] + ad4[k];
                qq = (qq > 0.f) ? qq : 0.2f * qq;
                o[k] = __expf(qq - e4[k]);
            }
            lw[ns][e - base] = o;
        }
        asm volatile("s_waitcnt lgkmcnt(0)" ::: "memory");
        // phase B: serial weighted accumulation, 4 independent chains
        int n = cend - base;
        int j = 0;
        for (; j + 4 <= n; j += 4) {
            int s0 = csr[base + j], s1 = csr[base + j + 1];
            int s2 = csr[base + j + 2], s3 = csr[base + j + 3];
            float w0 = lw[ns][j + 0][hd];
            float w1 = lw[ns][j + 1][hd];
            float w2 = lw[ns][j + 2][hd];
            float w3 = lw[ns][j + 3][hd];
            uint2 v0 = *(const uint2*)(hh + s0 * 128 + c0);
            uint2 v1 = *(const uint2*)(hh + s1 * 128 + c0);
            uint2 v2 = *(const uint2*)(hh + s2 * 128 + c0);
            uint2 v3 = *(const uint2*)(hh + s3 * 128 + c0);
            dacc[0] += w0;
            xacc[0][0] += w0 * bf2f((unsigned short)(v0.x & 0xFFFFu));
            xacc[0][1] += w0 * bf2f((unsigned short)(v0.x >> 16));
            xacc[0][2] += w0 * bf2f((unsigned short)(v0.y & 0xFFFFu));
            xacc[0][3] += w0 * bf2f((unsigned short)(v0.y >> 16));
            dacc[1] += w1;
            xacc[1][0] += w1 * bf2f((unsigned short)(v1.x & 0xFFFFu));
            xacc[1][1] += w1 * bf2f((unsigned short)(v1.x >> 16));
            xacc[1][2] += w1 * bf2f((unsigned short)(v1.y & 0xFFFFu));
            xacc[1][3] += w1 * bf2f((unsigned short)(v1.y >> 16));
            dacc[2] += w2;
            xacc[2][0] += w2 * bf2f((unsigned short)(v2.x & 0xFFFFu));
            xacc[2][1] += w2 * bf2f((unsigned short)(v2.x >> 16));
            xacc[2][2] += w2 * bf2f((unsigned short)(v2.y & 0xFFFFu));
            xacc[2][3] += w2 * bf2f((unsigned short)(v2.y >> 16));
            dacc[3] += w3;
            xacc[3][0] += w3 * bf2f((unsigned short)(v3.x & 0xFFFFu));
            xacc[3][1] += w3 * bf2f((unsigned short)(v3.x >> 16));
            xacc[3][2] += w3 * bf2f((unsigned short)(v3.y & 0xFFFFu));
            xacc[3][3] += w3 * bf2f((unsigned short)(v3.y >> 16));
        }
        for (; j < n; ++j) {
            int s0 = csr[base + j];
            float w0 = lw[ns][j][hd];
            uint2 v0 = *(const uint2*)(hh + s0 * 128 + c0);
            dacc[0] += w0;
            xacc[0][0] += w0 * bf2f((unsigned short)(v0.x & 0xFFFFu));
            xacc[0][1] += w0 * bf2f((unsigned short)(v0.x >> 16));
            xacc[0][2] += w0 * bf2f((unsigned short)(v0.y & 0xFFFFu));
            xacc[0][3] += w0 * bf2f((unsigned short)(v0.y >> 16));
        }
        if (cend < e1)
            asm volatile("s_waitcnt lgkmcnt(0)" ::: "memory");
    }
    float den = (dacc[0] + dacc[1]) + (dacc[2] + dacc[3]);
    f32x4 X;
#pragma unroll
    for (int k = 0; k < 4; ++k)
        X[k] = (xacc[0][k] + xacc[1][k]) + (xacc[2][k] + xacc[3][k]);
    float inv = 1.f / den;
    f32x4 bgv  = *(const f32x4*)(bg + c0);
    f32x4 ggv  = *(const f32x4*)(gg + c0);
    f32x4 bggv = *(const f32x4*)(bgg + c0);
    f32x4 o;
    float s = 0.f, ss = 0.f;
#pragma unroll
    for (int k = 0; k < 4; ++k) {
        o[k] = X[k] * inv + bgv[k];
        s += o[k]; ss += o[k] * o[k];
    }
#pragma unroll
    for (int m = 1; m <= 16; m <<= 1) {   // reduce within the 32-lane half only
        s += __shfl_xor(s, m, 64); ss += __shfl_xor(ss, m, 64);
    }
    float mu = s * (1.f / 128.f);
    float var = ss * (1.f / 128.f) - mu * mu;
    float rstd = rsqrtf(var + 1e-5f);
    f32x4 idv = *(const f32x4*)(h + node * 128 + c0);
    f32x4 r;
#pragma unroll
    for (int k = 0; k < 4; ++k) {
        float y = (o[k] - mu) * rstd * ggv[k] + bggv[k];
        r[k] = silu(y) + idv[k];
    }
    *(f32x4*)(h + node * 128 + c0) = r;
}

// ---------------- mean pool per graph (batch sorted); counts from hist ----------------
__global__ void pool_kernel(const float* __restrict__ h, const int* __restrict__ batch,
                            float* __restrict__ pooled) {
    int c = threadIdx.x;
    int r0 = blockIdx.x * 64;
    int rend = r0 + 64; if (rend > NN) rend = NN;
    int cur = batch[r0];
    float acc = 0.f;
    for (int r = r0; r < rend; ++r) {
        int b = batch[r];
        float v = h[r * 128 + c];
        if (b != cur) {
            atomicAdd(&pooled[cur * 128 + c], acc);
            acc = 0.f; cur = b;
        }
        acc += v;
    }
    atomicAdd(&pooled[cur * 128 + c], acc);
}

// ---------------- head: silu(LN(pooled/cnt @ Wp + bp)) -> f32 out ----------------
__global__ void final_kernel(const float* __restrict__ pooled, const float* __restrict__ cntArr,
                             const float* __restrict__ Wp, const float* __restrict__ bp,
                             const float* __restrict__ gp, const float* __restrict__ bep,
                             float* __restrict__ out) {
    __shared__ float p[128];
    __shared__ float red[128];
    int g = blockIdx.x, c = threadIdx.x;
    float cnt = cntArr[g]; if (cnt < 1.f) cnt = 1.f;
    p[c] = pooled[g * 128 + c] / cnt;
    __syncthreads();
    float acc = bp[c];
    for (int k = 0; k < 128; ++k) acc += p[k] * Wp[k * 128 + c];
    red[c] = acc;
    __syncthreads();
    if (c < 64) {
        float s = red[c] + red[c + 64];
#pragma unroll
        for (int m = 1; m <= 32; m <<= 1) s += __shfl_xor(s, m, 64);
        if (c == 0) red[0] = s;
    }
    __syncthreads();
    float mu = red[0] * (1.f / 128.f);
    __syncthreads();
    float dv = acc - mu;
    red[c] = dv * dv;
    __syncthreads();
    if (c < 64) {
        float s = red[c] + red[c + 64];
#pragma unroll
        for (int m = 1; m <= 32; m <<= 1) s += __shfl_xor(s, m, 64);
        if (c == 0) red[0] = s;
    }
    __syncthreads();
    float var = red[0] * (1.f / 128.f);
    float rstd = rsqrtf(var + 1e-5f);
    float y = dv * rstd * gp[c] + bep[c];
    out[g * 128 + c] = silu(y);
}

extern "C" void kernel_launch(void* const* d_in, const int* in_sizes, int n_in,
                              void* d_out, int out_size, void* d_ws, size_t ws_size,
                              hipStream_t stream) {
    const float* x    = (const float*)d_in[0];
    const int*   eidx = (const int*)d_in[1];
    const int*   batch= (const int*)d_in[2];
    const float* W0   = (const float*)d_in[3];
    const float* b0   = (const float*)d_in[4];
    const float* g0   = (const float*)d_in[5];
    const float* be0  = (const float*)d_in[6];
    const float* Wg   = (const float*)d_in[7];
    const float* atts = (const float*)d_in[8];
    const float* attd = (const float*)d_in[9];
    const float* bg   = (const float*)d_in[10];
    const float* gg   = (const float*)d_in[11];
    const float* bgg  = (const float*)d_in[12];
    const float* Wp   = (const float*)d_in[13];
    const float* bp   = (const float*)d_in[14];
    const float* gp   = (const float*)d_in[15];
    const float* bep  = (const float*)d_in[16];

    char* ws = (char*)d_ws;
    size_t off = 0;
    auto alloc = [&](size_t bytes) {
        void* p = ws + off;
        off = (off + bytes + 255) & ~(size_t)255;
        return p;
    };
    float*          h        = (float*)alloc((size_t)NPAD * 128 * 4);
    unsigned short* hh       = (unsigned short*)alloc((size_t)NN * 128 * 2);
    float*          a_s      = (float*)alloc((size_t)NN * 4 * 4);
    float*          a_d      = (float*)alloc((size_t)NN * 4 * 4);
    float*          es       = (float*)alloc((size_t)NN * 4 * 4);
    int*            offs     = (int*)alloc((size_t)(NN + 1) * 4);
    int*            counts   = (int*)alloc((size_t)NN * 4);
    int*            csr      = (int*)alloc((size_t)EPE * 4);
    unsigned*       binned   = (unsigned*)alloc((size_t)EPE * 4);
    int*            hist_blk = (int*)alloc((size_t)NBLK * NB * 4);
    int*            blkOfs   = (int*)alloc((size_t)NBLK * NB * 4);
    int*            bktBase  = (int*)alloc((size_t)NB * 4);
    int*            parts    = (int*)alloc(256 * 4);
    unsigned short* WT       = (unsigned short*)alloc(4 * 16384 * 2);
    float*          pooled   = (float*)alloc((size_t)(BGR * 128 + BGR) * 4);
    float*          cntArr   = pooled + BGR * 128;

    hipMemsetAsync(counts, 0, (size_t)NN * 4, stream);
    hipMemsetAsync(pooled, 0, (size_t)(BGR * 128 + BGR) * 4, stream);

    transpose_w<<<4, 256, 0, stream>>>(W0, Wg, WT);
    count_edges<<<(EPE + 255) / 256, 256, 0, stream>>>(eidx, counts, batch, cntArr);
    bucket_hist<<<NBLK, 256, 0, stream>>>(eidx, hist_blk);
    int nb = (NN + 255) / 256;
    scan1<<<nb, 256, 0, stream>>>(counts, offs, parts);
    scan2<<<1, 256, 0, stream>>>(parts, nb);
    scan3<<<nb, 256, 0, stream>>>(offs, parts);
    scan_buckets<<<1, 128, 0, stream>>>(hist_blk, blkOfs, bktBase);
    bin_edges<<<NBLK, 256, 0, stream>>>(eidx, blkOfs, binned);
    build_csr<<<NB, 256, 0, stream>>>(binned, offs, csr);

    gemm_encoder<<<NPAD / 64, 256, 0, stream>>>(x, WT, b0, g0, be0, h);
    for (int l = 0; l < 3; ++l) {
        gemm_gat<<<NPAD / 64, 256, 0, stream>>>(h, WT + (l + 1) * 16384,
                                                atts + l * 128, attd + l * 128,
                                                hh, a_s, a_d, es);
        gat_aggregate<<<NN / 8, 256, 0, stream>>>(offs, csr, a_s, a_d, es, hh, h,
                                                  bg + l * 128, gg + l * 128,
                                                  bgg + l * 128);
    }
    pool_kernel<<<(NN + 63) / 64, 128, 0, stream>>>(h, batch, pooled);
    final_kernel<<<BGR, 128, 0, stream>>>(pooled, cntArr, Wp, bp, gp, bep, (float*)d_out);
}